// Round 6
// baseline (230.344 us; speedup 1.0000x reference)
//
#include <hip/hip_runtime.h>
#include <hip/hip_fp16.h>

#define N_NODES 50000
#define N_EDGES 800000
#define NPAD    50176          // 196*256: graph-2 node base, bucket-aligned
#define NBKT    392            // (2*NPAD)/256 buckets of 256 nodes
#define BCAP    6144           // bucket capacity; mean 4082, sigma 64 -> +32 sigma
#define PBN     16             // nodes per pull block (NPAD % PBN == 0)
#define LCAP    1024           // staged csr window cap (mean 256, +48 sigma)
#define X1S     136            // LDS X1 stride (halfs): 272 B rows, 16B-aligned
#define EPB     16384          // R6: 4096->16384. binA time is linear in block
                               // count (R0/R3/R4/R5 fit: ~61ns/block) => per-word
                               // device-atomic reserve chain. 98 blocks: chain
                               // 391->98 steps (~-18us). LDS 136KB, 1 blk/CU --
                               // occupancy proven irrelevant (R3).
#define NEB     ((2 * N_EDGES + EPB - 1) / EPB)   // 98 edge blocks
#define CSTRIDE 16             // one atomic counter per 64B line (R5)
static_assert(N_NODES < 65536, "u16 CSR requires local node ids < 65536");
static_assert(EPB <= 65536, "u16 sidx requires EPB <= 65536");
// LAYOUT RULE: all intermediate buffers indexed by PADDED gid (g*NPAD + i).
// Compaction to the harness's [2*N_NODES,64] output only at pull-2's store.
// Gather/GEMM feature buffers are fp16; all accumulation fp32 (MFMA C=f32).

typedef _Float16 __attribute__((ext_vector_type(8))) half8;
typedef float    __attribute__((ext_vector_type(4))) floatx4;

// Per-block edge-index stride detection (int64 vs int32): odd 32-bit words of
// little-endian int64 with values < 2^31 are all zero.
__device__ __forceinline__ int detect_stride_block(const int* raw1, int* sflag) {
    int odd = 0;
    for (int i = threadIdx.x; i < 2048; i += 256) odd |= raw1[2 * i + 1];
    if (threadIdx.x == 0) *sflag = 0;
    __syncthreads();
    if (odd) atomicOr(sflag, 1);
    __syncthreads();
    return *sflag ? 1 : 2;
}

// ---------------------------------------------------------------------------
// Pass A, SINGLE-PASS, NEB edge-blocks x EPB edges: LDS hist -> line-padded
// global reserve -> local scan -> local counting sort -> coalesced flush.
// Entry: (dst_in_bucket << 16) | src_local. Blocks NEB/NEB+1 pack W1/W2
// into MFMA B-fragment order. Last-finishing edge block (device-scope done
// counter on its OWN line) computes the bucket-base exclusive scan -> bexcl.
// ---------------------------------------------------------------------------
__global__ __launch_bounds__(256) void binA_k(const int* __restrict__ raw1,
        const int* __restrict__ raw2, const float* __restrict__ W1,
        const float* __restrict__ W2, unsigned* __restrict__ bcount,
        unsigned* __restrict__ bbuf, _Float16* __restrict__ Wf1,
        _Float16* __restrict__ Wf2, unsigned* __restrict__ done,
        int* __restrict__ bexcl) {
    if (blockIdx.x >= NEB) {                 // fused wprep
        const int wsel = blockIdx.x - NEB;
        const float* W = wsel ? W2 : W1;
        _Float16* Wf = wsel ? Wf2 : Wf1;
        const int M = wsel ? 64 : 128;
        const int NT = M / 16;
        for (int i = threadIdx.x; i < 8192; i += 256) {   // 16 frags x 512
            int f = i >> 9, r = i & 511;
            int lane = r >> 3, j = r & 7;
            int kc = f / NT, nt = f % NT;
            int k = kc * 32 + (lane >> 4) * 8 + j;
            int m = nt * 16 + (lane & 15);
            Wf[i] = (_Float16)W[k * M + m];
        }
        return;
    }
    __shared__ unsigned ent[EPB];            // 64 KB
    __shared__ unsigned short ebkt[EPB];     // 32 KB
    __shared__ unsigned short sidx[EPB];     // 32 KB: bucket-sorted entry indices
    __shared__ unsigned hist[NBKT], gofs[NBKT];
    __shared__ int lofs[NBKT], cur[NBKT];
    __shared__ int t2[512];
    __shared__ int sflag;
    const int stride = detect_stride_block(raw1, &sflag);
    const int tid = threadIdx.x;
    for (int b = tid; b < NBKT; b += 256) hist[b] = 0u;
    __syncthreads();
    const long long e0 = (long long)blockIdx.x * EPB;
    const int scnt = (int)min((long long)EPB, 2LL * N_EDGES - e0);
    #pragma unroll 4
    for (int it = 0; it < EPB / 256; it++) {
        int i = it * 256 + tid;
        if (i < scnt) {
            long long e = e0 + i;
            int g2 = e >= N_EDGES;
            const int* raw = g2 ? raw2 : raw1;
            long long el = e - (g2 ? N_EDGES : 0);
            int s = raw[el * stride];
            int d = raw[((long long)N_EDGES + el) * stride];
            int gid = g2 * NPAD + d;
            int bkt = gid >> 8;
            ent[i] = ((unsigned)(gid & 255) << 16) | (unsigned)s;
            ebkt[i] = (unsigned short)bkt;
            atomicAdd(&hist[bkt], 1u);
        }
    }
    __syncthreads();
    // reserve global runs (one counter per cache line; chain depth = NEB)
    for (int b = tid; b < NBKT; b += 256) {
        unsigned c = hist[b];
        gofs[b] = c ? atomicAdd(&bcount[b * CSTRIDE], c) : 0u;
    }
    // exclusive scan of hist -> lofs (padded 512 Hillis-Steele)
    t2[tid] = (tid < NBKT) ? (int)hist[tid] : 0;
    t2[tid + 256] = (tid + 256 < NBKT) ? (int)hist[tid + 256] : 0;
    __syncthreads();
    #pragma unroll
    for (int off = 1; off < 512; off <<= 1) {
        int a0 = (tid >= off) ? t2[tid - off] : 0;
        int a1 = (tid + 256 >= off) ? t2[tid + 256 - off] : 0;
        __syncthreads();
        t2[tid] += a0; t2[tid + 256] += a1;
        __syncthreads();
    }
    if (tid < NBKT) { int l = t2[tid] - (int)hist[tid]; lofs[tid] = l; cur[tid] = l; }
    if (tid + 256 < NBKT) {
        int l = t2[tid + 256] - (int)hist[tid + 256];
        lofs[tid + 256] = l; cur[tid + 256] = l;
    }
    __syncthreads();
    // place entry indices in bucket-sorted order
    for (int i = tid; i < scnt; i += 256) {
        int bkt = (int)ebkt[i];
        int p = atomicAdd(&cur[bkt], 1);
        sidx[p] = (unsigned short)i;
    }
    __syncthreads();
    // coalesced flush: consecutive i within a bucket run -> consecutive addrs
    for (int i = tid; i < scnt; i += 256) {
        int e = (int)sidx[i];
        int bkt = (int)ebkt[e];
        unsigned pos = gofs[bkt] + (unsigned)(i - lofs[bkt]);
        if (pos < BCAP) bbuf[(size_t)bkt * BCAP + pos] = ent[e];
    }
    // ---- last-finisher computes exclusive bucket scan (no block ever waits) ----
    __syncthreads();
    __shared__ int lastf;
    if (tid == 0) {
        __threadfence();
        lastf = (atomicAdd(done, 1u) == (unsigned)(NEB - 1)) ? 1 : 0;
    }
    __syncthreads();
    if (lastf) {
        int v0 = (tid < NBKT) ? (int)atomicAdd(&bcount[tid * CSTRIDE], 0u) : 0;
        int v1 = (tid + 256 < NBKT) ? (int)atomicAdd(&bcount[(tid + 256) * CSTRIDE], 0u) : 0;
        t2[tid] = v0; t2[tid + 256] = v1;
        __syncthreads();
        #pragma unroll
        for (int off = 1; off < 512; off <<= 1) {
            int a0 = (tid >= off) ? t2[tid - off] : 0;
            int a1 = (tid + 256 >= off) ? t2[tid + 256 - off] : 0;
            __syncthreads();
            t2[tid] += a0; t2[tid + 256] += a1;
            __syncthreads();
        }
        if (tid < NBKT) bexcl[tid] = t2[tid] - v0;
        if (tid + 256 < NBKT) bexcl[tid + 256] = t2[tid + 256] - v1;
    }
}

// ---------------------------------------------------------------------------
// Pass B: one block per bucket. CSR base read from bexcl; per-node degree +
// rowptr + dinv; LDS-cursor CSR scatter; fused fp16 prescale sxh = dinv * x.
// Wave __shfl_up scan (6 shuffles + 2 barriers) instead of 16-barrier H-S.
// ---------------------------------------------------------------------------
__global__ __launch_bounds__(256) void buildB_k(const unsigned* __restrict__ bcount,
        const int* __restrict__ bexcl, const unsigned* __restrict__ bbuf,
        const float* __restrict__ x1, const float* __restrict__ x2,
        unsigned short* __restrict__ csr, int* __restrict__ rowptr,
        float* __restrict__ dinv, __half* __restrict__ sxh) {
    __shared__ unsigned ent[BCAP];
    __shared__ int deg[256], cur[256];
    __shared__ int wsum[4];
    __shared__ float sdinv[256];
    const int b = blockIdx.x, tid = threadIdx.x;
    const int cnt = min((int)bcount[b * CSTRIDE], BCAP);
    const int eb = bexcl[b];
    for (int i = tid; i < cnt; i += 256) ent[i] = bbuf[(size_t)b * BCAP + i];
    deg[tid] = 0;
    __syncthreads();
    for (int i = tid; i < cnt; i += 256) atomicAdd(&deg[ent[i] >> 16], 1);
    __syncthreads();
    const int v = deg[tid];
    const int lane = tid & 63, w = tid >> 6;
    int x = v;                                    // wave-inclusive scan
    #pragma unroll
    for (int off = 1; off < 64; off <<= 1) {
        int y = __shfl_up(x, off);
        if (lane >= off) x += y;
    }
    if (lane == 63) wsum[w] = x;
    __syncthreads();
    int wpre = 0;
    #pragma unroll
    for (int i = 0; i < 4; i++) wpre += (i < w) ? wsum[i] : 0;
    const int excl = x + wpre - v;
    cur[tid] = excl;
    const int gid = b * 256 + tid;
    float dv = rsqrtf((float)v + 1.0f);          // +1 self-loop
    rowptr[gid] = eb + excl;
    dinv[gid] = dv;
    sdinv[tid] = dv;
    if (b == NBKT - 1 && tid == 255) rowptr[2 * NPAD] = eb + excl + v;
    __syncthreads();
    for (int i = tid; i < cnt; i += 256) {
        unsigned p = ent[i];
        int pos = atomicAdd(&cur[p >> 16], 1);
        csr[eb + pos] = (unsigned short)(p & 0xFFFFu);
    }
    const int g2 = (b * 256) >= NPAD;
    const float* x0 = g2 ? x2 : x1;
    const int lbase = b * 256 - (g2 ? NPAD : 0);
    for (int i = tid; i < 256 * 16; i += 256) {
        int n = i >> 4, q = i & 15;
        int local = lbase + n;
        __half2 lo = __floats2half2_rn(0.f, 0.f), hi = lo;
        if (local < N_NODES) {
            float4 vx = *(const float4*)&x0[((size_t)local * 16 + q) * 4];
            float dn = sdinv[n];
            lo = __floats2half2_rn(vx.x * dn, vx.y * dn);
            hi = __floats2half2_rn(vx.z * dn, vx.w * dn);
        }
        uint2 u; u.x = *(unsigned*)&lo; u.y = *(unsigned*)&hi;
        *(uint2*)&sxh[(size_t)(b * 256 + n) * 64 + q * 4] = u;
    }
}

// ---------------------------------------------------------------------------
// Pull aggregation, NODE-PER-SUB: block = 16 nodes, 4 waves; each wave's 4
// sub-quads own ONE node each; lane accumulates its 8-byte slice in-register
// (no cross-lane reduce). Predicated gathers; full-64-lane self-load/store.
// ---------------------------------------------------------------------------
template<bool BIAS_RELU, bool COMPACT_OUT, bool OUT_HALF>
__global__ __launch_bounds__(256) void pull_agg_k(const __half* __restrict__ sh,
        const unsigned short* __restrict__ csr, const int* __restrict__ rowptr,
        const float* __restrict__ dinv, const float* __restrict__ bias,
        void* __restrict__ outv) {
    __shared__ unsigned short lcsr[LCAP];
    __shared__ int lrp[PBN + 1];
    __shared__ float ldv[PBN];
    const int tid = threadIdx.x;
    const int n0 = blockIdx.x * PBN;             // padded node base (no straddle)
    const int g2 = n0 >= NPAD;
    const int gbase = g2 ? NPAD : 0;
    if (tid <= PBN) lrp[tid] = rowptr[n0 + tid];
    if (tid < PBN)  ldv[tid] = dinv[n0 + tid];
    __syncthreads();
    const int wb = lrp[0];
    const int wcnt = min(lrp[PBN] - wb, LCAP);
    for (int i = tid; i < wcnt; i += 256) lcsr[i] = csr[wb + i];
    __syncthreads();
    const int wv = tid >> 6, lane = tid & 63;
    const int sub = lane >> 4, fl = lane & 15;
    const int n = wv * 4 + sub;                  // this lane's node (0..15)
    const int d = n0 + n;
    const int jfull = lrp[n + 1] - wb;
    const int jb = min(lrp[n] - wb, wcnt);
    const int je = min(jfull, wcnt);
    float4 acc = {0.f, 0.f, 0.f, 0.f};
    for (int j = jb; j < je; j += 8) {
        uint2 u[8];
        #pragma unroll
        for (int k = 0; k < 8; k++) {
            uint2 v; v.x = 0u; v.y = 0u;
            int idx = j + k;
            if (idx < je) {                      // sub-uniform guard: no request if off
                int s = (int)lcsr[idx] + gbase;
                v = *(const uint2*)&sh[(size_t)s * 64 + fl * 4];
            }
            u[k] = v;
        }
        #pragma unroll
        for (int k = 0; k < 8; k += 2) {
            __half2 pa = __hadd2(*(__half2*)&u[k].x, *(__half2*)&u[k + 1].x);
            __half2 pb = __hadd2(*(__half2*)&u[k].y, *(__half2*)&u[k + 1].y);
            float2 fa = __half22float2(pa), fb = __half22float2(pb);
            acc.x += fa.x; acc.y += fa.y; acc.z += fb.x; acc.w += fb.y;
        }
    }
    for (int j2 = je; j2 < jfull; j2++) {        // LCAP overflow: global, rare
        int s = (int)csr[wb + j2] + gbase;
        uint2 u = *(const uint2*)&sh[(size_t)s * 64 + fl * 4];
        float2 f0 = __half22float2(*(__half2*)&u.x);
        float2 f1 = __half22float2(*(__half2*)&u.y);
        acc.x += f0.x; acc.y += f0.y; acc.z += f1.x; acc.w += f1.y;
    }
    uint2 su = *(const uint2*)&sh[(size_t)d * 64 + fl * 4];
    float2 sf0 = __half22float2(*(__half2*)&su.x);
    float2 sf1 = __half22float2(*(__half2*)&su.y);
    float dv = ldv[n];
    float4 o;
    o.x = (acc.x + sf0.x) * dv;
    o.y = (acc.y + sf0.y) * dv;
    o.z = (acc.z + sf1.x) * dv;
    o.w = (acc.w + sf1.y) * dv;
    if (BIAS_RELU) {
        float4 bv = *(const float4*)&bias[fl * 4];
        o.x = fmaxf(o.x + bv.x, 0.f);
        o.y = fmaxf(o.y + bv.y, 0.f);
        o.z = fmaxf(o.z + bv.z, 0.f);
        o.w = fmaxf(o.w + bv.w, 0.f);
    }
    if (OUT_HALF) {
        __half2 lo = __floats2half2_rn(o.x, o.y);
        __half2 hi = __floats2half2_rn(o.z, o.w);
        uint2 u2; u2.x = *(unsigned*)&lo; u2.y = *(unsigned*)&hi;
        *(uint2*)&((__half*)outv)[(size_t)d * 64 + fl * 4] = u2;     // padded
    } else {
        int local = d - gbase;
        if (!COMPACT_OUT) {
            *(float4*)&((float*)outv)[(size_t)d * 64 + fl * 4] = o;
        } else if (local < N_NODES) {
            size_t orow = (size_t)(g2 ? N_NODES + local : local);
            floatx4 ov; ov.x = o.x; ov.y = o.y; ov.z = o.z; ov.w = o.w;
            __builtin_nontemporal_store(ov,
                (floatx4*)&((float*)outv)[orow * 64 + fl * 4]);
        }
    }
}

// ---------------------------------------------------------------------------
// FUSED double MFMA GEMM [R11-verified]: GH = dinv * (relu(Y@W1 + b1) @ W2),
// per 128-row block, X1 routed through LDS (stride X1S=136 halfs).
// C/D layout col=lane&15, row=(lane>>4)*4+reg. Grid 784 exact.
// ---------------------------------------------------------------------------
__global__ __launch_bounds__(256) void gemm12_k(const _Float16* __restrict__ Y,
        const _Float16* __restrict__ Wf1, const float* __restrict__ b1,
        const _Float16* __restrict__ Wf2, const float* __restrict__ dinv,
        _Float16* __restrict__ GH) {
    __shared__ _Float16 X1l[128 * X1S];      // 34.8 KB
    const int tid = threadIdx.x;
    const int wv = tid >> 6, lane = tid & 63;
    const int quad = lane >> 4, c = lane & 15;
    const int lrow0 = wv * 32;               // wave's 32 local rows
    const int grow0 = blockIdx.x * 128 + lrow0;
    // ---- phase 1: X1 = relu(Y @ W1 + b1) -> LDS ----
    {
        half8 bf[2][8];                      // K=64 (KC=2), M=128 (NT=8)
        #pragma unroll
        for (int kc = 0; kc < 2; kc++)
            #pragma unroll
            for (int nt = 0; nt < 8; nt++)
                bf[kc][nt] = *(const half8*)&Wf1[((kc * 8 + nt) * 64 + lane) * 8];
        floatx4 acc[2][8] = {};
        #pragma unroll
        for (int rt = 0; rt < 2; rt++) {
            half8 a[2];
            #pragma unroll
            for (int kc = 0; kc < 2; kc++)
                a[kc] = *(const half8*)&Y[(size_t)(grow0 + rt * 16 + c) * 64 + kc * 32 + quad * 8];
            #pragma unroll
            for (int nt = 0; nt < 8; nt++)
                #pragma unroll
                for (int kc = 0; kc < 2; kc++)
                    acc[rt][nt] = __builtin_amdgcn_mfma_f32_16x16x32_f16(
                        a[kc], bf[kc][nt], acc[rt][nt], 0, 0, 0);
        }
        float bv[8];
        #pragma unroll
        for (int nt = 0; nt < 8; nt++) bv[nt] = b1[nt * 16 + c];
        #pragma unroll
        for (int rt = 0; rt < 2; rt++)
            #pragma unroll
            for (int nt = 0; nt < 8; nt++)
                #pragma unroll
                for (int reg = 0; reg < 4; reg++) {
                    float v = fmaxf(acc[rt][nt][reg] + bv[nt], 0.f);
                    X1l[(lrow0 + rt * 16 + quad * 4 + reg) * X1S + nt * 16 + c] = (_Float16)v;
                }
    }
    __syncthreads();
    // ---- phase 2: GH = dinv * (X1 @ W2) ----
    {
        half8 bf[4][4];                      // K=128 (KC=4), M=64 (NT=4)
        #pragma unroll
        for (int kc = 0; kc < 4; kc++)
            #pragma unroll
            for (int nt = 0; nt < 4; nt++)
                bf[kc][nt] = *(const half8*)&Wf2[((kc * 4 + nt) * 64 + lane) * 8];
        floatx4 acc[2][4] = {};
        #pragma unroll
        for (int rt = 0; rt < 2; rt++) {
            half8 a[4];
            #pragma unroll
            for (int kc = 0; kc < 4; kc++)
                a[kc] = *(const half8*)&X1l[(lrow0 + rt * 16 + c) * X1S + kc * 32 + quad * 8];
            #pragma unroll
            for (int nt = 0; nt < 4; nt++)
                #pragma unroll
                for (int kc = 0; kc < 4; kc++)
                    acc[rt][nt] = __builtin_amdgcn_mfma_f32_16x16x32_f16(
                        a[kc], bf[kc][nt], acc[rt][nt], 0, 0, 0);
        }
        #pragma unroll
        for (int rt = 0; rt < 2; rt++) {
            const int rbase = grow0 + rt * 16 + quad * 4;
            float4 dvv = *(const float4*)&dinv[rbase];
            #pragma unroll
            for (int nt = 0; nt < 4; nt++)
                #pragma unroll
                for (int reg = 0; reg < 4; reg++) {
                    float v = acc[rt][nt][reg] * ((const float*)&dvv)[reg];
                    GH[(size_t)(rbase + reg) * 64 + nt * 16 + c] = (_Float16)v;
                }
        }
    }
}

extern "C" void kernel_launch(void* const* d_in, const int* in_sizes, int n_in,
                              void* d_out, int out_size, void* d_ws, size_t ws_size,
                              hipStream_t stream) {
    const float* x1 = (const float*)d_in[0];
    const int*   e1 = (const int*)d_in[1];
    const float* x2 = (const float*)d_in[2];
    const int*   e2 = (const int*)d_in[3];
    const float* W1 = (const float*)d_in[4];
    const float* b1 = (const float*)d_in[5];
    const float* W2 = (const float*)d_in[6];
    const float* b2 = (const float*)d_in[7];
    float* out = (float*)d_out;

    // Workspace (~45 MB), 256 B-aligned chunks.
    char* p = (char*)d_ws;
    auto alloc = [&](size_t bytes) { char* r = p; p += (bytes + 255) & ~(size_t)255; return r; };
    unsigned* bcount = (unsigned*)alloc((size_t)(NBKT * CSTRIDE + CSTRIDE) * 4);
    unsigned* done   = bcount + NBKT * CSTRIDE;    // own cache line
    int*      bexcl  = (int*)alloc(NBKT * 4);
    float*    dinv   = (float*)alloc((size_t)2 * NPAD * 4);
    int*      rowptr = (int*)alloc(((size_t)2 * NPAD + 1) * 4);
    unsigned* bbuf   = (unsigned*)alloc((size_t)NBKT * BCAP * 4);
    unsigned short* csr = (unsigned short*)alloc((size_t)2 * N_EDGES * 2);
    __half*   sxh    = (__half*)alloc((size_t)2 * NPAD * 64 * 2);    // fp16 feats
    _Float16* bufYh  = (_Float16*)alloc((size_t)2 * NPAD * 64 * 2);  // fp16 Y
    _Float16* Wf1    = (_Float16*)alloc(8192 * 2);
    _Float16* Wf2    = (_Float16*)alloc(8192 * 2);
    __half*   gh     = sxh;   // alias: sxh dead after pull-1; gemm12 writes gh

    // ---- CSR build + dinv + fp16 prescale + W fragment pack (fused) ----
    (void)hipMemsetAsync(bcount, 0, (size_t)(NBKT * CSTRIDE + CSTRIDE) * 4, stream);
    binA_k<<<NEB + 2, 256, 0, stream>>>(e1, e2, W1, W2, bcount, bbuf, Wf1, Wf2, done, bexcl);
    buildB_k<<<NBKT, 256, 0, stream>>>(bcount, bexcl, bbuf, x1, x2, csr, rowptr, dinv, sxh);

    // ---- layer 1 agg: Y = A_hat @ X (fp16) ----
    pull_agg_k<false, false, true><<<2 * NPAD / PBN, 256, 0, stream>>>(
        sxh, csr, rowptr, dinv, nullptr, bufYh);
    // ---- fused GEMMs: G' = fp16(dinv * (relu(Y@W1+b1) @ W2)) ----
    gemm12_k<<<784, 256, 0, stream>>>(bufYh, Wf1, b1, Wf2, dinv, (_Float16*)gh);
    // ---- layer 2 agg + epilogue: out = relu(dinv*(sum+self)+b2) ----
    pull_agg_k<true, true, false><<<2 * NPAD / PBN, 256, 0, stream>>>(
        gh, csr, rowptr, dinv, b2, out);
}

// Round 7
// 203.397 us; speedup vs baseline: 1.1325x; 1.1325x over previous
//
#include <hip/hip_runtime.h>
#include <hip/hip_fp16.h>

#define N_NODES 50000
#define N_EDGES 800000
#define NPAD    50176          // 196*256: graph-2 node base, bucket-aligned
#define NBKT    392            // (2*NPAD)/256 buckets of 256 nodes
#define BCAP    6144           // bucket capacity; mean 4082, sigma 64 -> +32 sigma
#define PBN     16             // nodes per pull block (NPAD % PBN == 0)
#define LCAP    1024           // staged csr window cap (mean 256, +48 sigma)
#define X1S     136            // LDS X1 stride (halfs): 272 B rows, 16B-aligned
#define EPB     4096           // R7: back to measured-best (R5: 42us). R3 (2048)
                               // and R6 (16384) both worse: binA is per-block
                               // latency-chain bound, ~21us/block, flat in EPB.
#define NEB     ((2 * N_EDGES + EPB - 1) / EPB)   // 391 edge blocks
#define CSTRIDE 16             // one atomic counter per 64B line (R5)
static_assert(N_NODES < 65536, "u16 CSR requires local node ids < 65536");
static_assert(EPB <= 65536, "u16 sidx requires EPB <= 65536");
// LAYOUT RULE: all intermediate buffers indexed by PADDED gid (g*NPAD + i).
// Compaction to the harness's [2*N_NODES,64] output only at pull-2's store.
// Gather/GEMM feature buffers are fp16; all accumulation fp32 (MFMA C=f32).

typedef _Float16 __attribute__((ext_vector_type(8))) half8;
typedef float    __attribute__((ext_vector_type(4))) floatx4;

// Per-block edge-index stride detection (int64 vs int32): odd 32-bit words of
// little-endian int64 with values < 2^31 are all zero.
__device__ __forceinline__ int detect_stride_block(const int* raw1, int* sflag) {
    int odd = 0;
    for (int i = threadIdx.x; i < 2048; i += 256) odd |= raw1[2 * i + 1];
    if (threadIdx.x == 0) *sflag = 0;
    __syncthreads();
    if (odd) atomicOr(sflag, 1);
    __syncthreads();
    return *sflag ? 1 : 2;
}

// ---------------------------------------------------------------------------
// Pass A, SINGLE-PASS, NEB edge-blocks x EPB edges: LDS hist -> line-padded
// global reserve -> local scan -> local counting sort -> coalesced flush.
// Entry: (dst_in_bucket << 16) | src_local. Blocks NEB/NEB+1 pack W1/W2
// into MFMA B-fragment order. Last-finishing edge block (device-scope done
// counter on its OWN line) computes the bucket-base exclusive scan -> bexcl.
// ---------------------------------------------------------------------------
__global__ __launch_bounds__(256) void binA_k(const int* __restrict__ raw1,
        const int* __restrict__ raw2, const float* __restrict__ W1,
        const float* __restrict__ W2, unsigned* __restrict__ bcount,
        unsigned* __restrict__ bbuf, _Float16* __restrict__ Wf1,
        _Float16* __restrict__ Wf2, unsigned* __restrict__ done,
        int* __restrict__ bexcl) {
    if (blockIdx.x >= NEB) {                 // fused wprep
        const int wsel = blockIdx.x - NEB;
        const float* W = wsel ? W2 : W1;
        _Float16* Wf = wsel ? Wf2 : Wf1;
        const int M = wsel ? 64 : 128;
        const int NT = M / 16;
        for (int i = threadIdx.x; i < 8192; i += 256) {   // 16 frags x 512
            int f = i >> 9, r = i & 511;
            int lane = r >> 3, j = r & 7;
            int kc = f / NT, nt = f % NT;
            int k = kc * 32 + (lane >> 4) * 8 + j;
            int m = nt * 16 + (lane & 15);
            Wf[i] = (_Float16)W[k * M + m];
        }
        return;
    }
    __shared__ unsigned ent[EPB];            // 16 KB
    __shared__ unsigned short ebkt[EPB];     // 8 KB
    __shared__ unsigned short sidx[EPB];     // 8 KB: bucket-sorted entry indices
    __shared__ unsigned hist[NBKT], gofs[NBKT];
    __shared__ int lofs[NBKT], cur[NBKT];
    __shared__ int t2[512];
    __shared__ int sflag;
    const int stride = detect_stride_block(raw1, &sflag);
    const int tid = threadIdx.x;
    for (int b = tid; b < NBKT; b += 256) hist[b] = 0u;
    __syncthreads();
    const long long e0 = (long long)blockIdx.x * EPB;
    const int scnt = (int)min((long long)EPB, 2LL * N_EDGES - e0);
    #pragma unroll 4
    for (int it = 0; it < EPB / 256; it++) {
        int i = it * 256 + tid;
        if (i < scnt) {
            long long e = e0 + i;
            int g2 = e >= N_EDGES;
            const int* raw = g2 ? raw2 : raw1;
            long long el = e - (g2 ? N_EDGES : 0);
            int s = raw[el * stride];
            int d = raw[((long long)N_EDGES + el) * stride];
            int gid = g2 * NPAD + d;
            int bkt = gid >> 8;
            ent[i] = ((unsigned)(gid & 255) << 16) | (unsigned)s;
            ebkt[i] = (unsigned short)bkt;
            atomicAdd(&hist[bkt], 1u);
        }
    }
    __syncthreads();
    // reserve global runs (one counter per cache line)
    for (int b = tid; b < NBKT; b += 256) {
        unsigned c = hist[b];
        gofs[b] = c ? atomicAdd(&bcount[b * CSTRIDE], c) : 0u;
    }
    // exclusive scan of hist -> lofs (padded 512 Hillis-Steele)
    t2[tid] = (tid < NBKT) ? (int)hist[tid] : 0;
    t2[tid + 256] = (tid + 256 < NBKT) ? (int)hist[tid + 256] : 0;
    __syncthreads();
    #pragma unroll
    for (int off = 1; off < 512; off <<= 1) {
        int a0 = (tid >= off) ? t2[tid - off] : 0;
        int a1 = (tid + 256 >= off) ? t2[tid + 256 - off] : 0;
        __syncthreads();
        t2[tid] += a0; t2[tid + 256] += a1;
        __syncthreads();
    }
    if (tid < NBKT) { int l = t2[tid] - (int)hist[tid]; lofs[tid] = l; cur[tid] = l; }
    if (tid + 256 < NBKT) {
        int l = t2[tid + 256] - (int)hist[tid + 256];
        lofs[tid + 256] = l; cur[tid + 256] = l;
    }
    __syncthreads();
    // place entry indices in bucket-sorted order
    for (int i = tid; i < scnt; i += 256) {
        int bkt = (int)ebkt[i];
        int p = atomicAdd(&cur[bkt], 1);
        sidx[p] = (unsigned short)i;
    }
    __syncthreads();
    // coalesced flush: consecutive i within a bucket run -> consecutive addrs
    for (int i = tid; i < scnt; i += 256) {
        int e = (int)sidx[i];
        int bkt = (int)ebkt[e];
        unsigned pos = gofs[bkt] + (unsigned)(i - lofs[bkt]);
        if (pos < BCAP) bbuf[(size_t)bkt * BCAP + pos] = ent[e];
    }
    // ---- last-finisher computes exclusive bucket scan (no block ever waits) ----
    __syncthreads();
    __shared__ int lastf;
    if (tid == 0) {
        __threadfence();
        lastf = (atomicAdd(done, 1u) == (unsigned)(NEB - 1)) ? 1 : 0;
    }
    __syncthreads();
    if (lastf) {
        int v0 = (tid < NBKT) ? (int)atomicAdd(&bcount[tid * CSTRIDE], 0u) : 0;
        int v1 = (tid + 256 < NBKT) ? (int)atomicAdd(&bcount[(tid + 256) * CSTRIDE], 0u) : 0;
        t2[tid] = v0; t2[tid + 256] = v1;
        __syncthreads();
        #pragma unroll
        for (int off = 1; off < 512; off <<= 1) {
            int a0 = (tid >= off) ? t2[tid - off] : 0;
            int a1 = (tid + 256 >= off) ? t2[tid + 256 - off] : 0;
            __syncthreads();
            t2[tid] += a0; t2[tid + 256] += a1;
            __syncthreads();
        }
        if (tid < NBKT) bexcl[tid] = t2[tid] - v0;
        if (tid + 256 < NBKT) bexcl[tid + 256] = t2[tid + 256] - v1;
    }
}

// ---------------------------------------------------------------------------
// Pass B: one block per bucket. CSR base read from bexcl; per-node degree +
// rowptr + dinv; LDS-cursor CSR scatter; fused fp16 prescale sxh = dinv * x.
// Wave __shfl_up scan (6 shuffles + 2 barriers) instead of 16-barrier H-S.
// ---------------------------------------------------------------------------
__global__ __launch_bounds__(256) void buildB_k(const unsigned* __restrict__ bcount,
        const int* __restrict__ bexcl, const unsigned* __restrict__ bbuf,
        const float* __restrict__ x1, const float* __restrict__ x2,
        unsigned short* __restrict__ csr, int* __restrict__ rowptr,
        float* __restrict__ dinv, __half* __restrict__ sxh) {
    __shared__ unsigned ent[BCAP];
    __shared__ int deg[256], cur[256];
    __shared__ int wsum[4];
    __shared__ float sdinv[256];
    const int b = blockIdx.x, tid = threadIdx.x;
    const int cnt = min((int)bcount[b * CSTRIDE], BCAP);
    const int eb = bexcl[b];
    for (int i = tid; i < cnt; i += 256) ent[i] = bbuf[(size_t)b * BCAP + i];
    deg[tid] = 0;
    __syncthreads();
    for (int i = tid; i < cnt; i += 256) atomicAdd(&deg[ent[i] >> 16], 1);
    __syncthreads();
    const int v = deg[tid];
    const int lane = tid & 63, w = tid >> 6;
    int x = v;                                    // wave-inclusive scan
    #pragma unroll
    for (int off = 1; off < 64; off <<= 1) {
        int y = __shfl_up(x, off);
        if (lane >= off) x += y;
    }
    if (lane == 63) wsum[w] = x;
    __syncthreads();
    int wpre = 0;
    #pragma unroll
    for (int i = 0; i < 4; i++) wpre += (i < w) ? wsum[i] : 0;
    const int excl = x + wpre - v;
    cur[tid] = excl;
    const int gid = b * 256 + tid;
    float dv = rsqrtf((float)v + 1.0f);          // +1 self-loop
    rowptr[gid] = eb + excl;
    dinv[gid] = dv;
    sdinv[tid] = dv;
    if (b == NBKT - 1 && tid == 255) rowptr[2 * NPAD] = eb + excl + v;
    __syncthreads();
    for (int i = tid; i < cnt; i += 256) {
        unsigned p = ent[i];
        int pos = atomicAdd(&cur[p >> 16], 1);
        csr[eb + pos] = (unsigned short)(p & 0xFFFFu);
    }
    const int g2 = (b * 256) >= NPAD;
    const float* x0 = g2 ? x2 : x1;
    const int lbase = b * 256 - (g2 ? NPAD : 0);
    for (int i = tid; i < 256 * 16; i += 256) {
        int n = i >> 4, q = i & 15;
        int local = lbase + n;
        __half2 lo = __floats2half2_rn(0.f, 0.f), hi = lo;
        if (local < N_NODES) {
            float4 vx = *(const float4*)&x0[((size_t)local * 16 + q) * 4];
            float dn = sdinv[n];
            lo = __floats2half2_rn(vx.x * dn, vx.y * dn);
            hi = __floats2half2_rn(vx.z * dn, vx.w * dn);
        }
        uint2 u; u.x = *(unsigned*)&lo; u.y = *(unsigned*)&hi;
        *(uint2*)&sxh[(size_t)(b * 256 + n) * 64 + q * 4] = u;
    }
}

// ---------------------------------------------------------------------------
// R7: FUSED pull-1 + both weight GEMMs. Each block's 16 nodes form COMPLETE
// Y rows after aggregation -> Y never hits global memory. Y -> LDS (stride
// 72 halfs, 2-way-free banks), G1 = relu(Y@W1+b1) -> LDS X1 (stride 136),
// G2 = dinv*(X1@W2) -> gh. 32 MFMAs / block across 4 waves. gh MUST NOT
// alias sxh (blocks still gather sxh while others write gh).
// ---------------------------------------------------------------------------
__global__ __launch_bounds__(256) void pull1g_k(const __half* __restrict__ sh,
        const unsigned short* __restrict__ csr, const int* __restrict__ rowptr,
        const float* __restrict__ dinv, const _Float16* __restrict__ Wf1,
        const float* __restrict__ b1, const _Float16* __restrict__ Wf2,
        _Float16* __restrict__ gh) {
    __shared__ unsigned short lcsr[LCAP];
    __shared__ int lrp[PBN + 1];
    __shared__ float ldv[PBN];
    __shared__ _Float16 Ylds[16 * 72];           // 2.3 KB, row stride 144 B
    __shared__ _Float16 X1l[16 * X1S];           // 4.4 KB
    const int tid = threadIdx.x;
    const int n0 = blockIdx.x * PBN;             // padded node base (no straddle)
    const int g2 = n0 >= NPAD;
    const int gbase = g2 ? NPAD : 0;
    if (tid <= PBN) lrp[tid] = rowptr[n0 + tid];
    if (tid < PBN)  ldv[tid] = dinv[n0 + tid];
    __syncthreads();
    const int wb = lrp[0];
    const int wcnt = min(lrp[PBN] - wb, LCAP);
    for (int i = tid; i < wcnt; i += 256) lcsr[i] = csr[wb + i];
    __syncthreads();
    const int wv = tid >> 6, lane = tid & 63;
    const int sub = lane >> 4, fl = lane & 15;   // sub == MFMA quad, fl == col
    const int n = wv * 4 + sub;                  // this lane's node (0..15)
    const int d = n0 + n;
    const int jfull = lrp[n + 1] - wb;
    const int jb = min(lrp[n] - wb, wcnt);
    const int je = min(jfull, wcnt);
    float4 acc = {0.f, 0.f, 0.f, 0.f};
    for (int j = jb; j < je; j += 8) {
        uint2 u[8];
        #pragma unroll
        for (int k = 0; k < 8; k++) {
            uint2 v; v.x = 0u; v.y = 0u;
            int idx = j + k;
            if (idx < je) {
                int s = (int)lcsr[idx] + gbase;
                v = *(const uint2*)&sh[(size_t)s * 64 + fl * 4];
            }
            u[k] = v;
        }
        #pragma unroll
        for (int k = 0; k < 8; k += 2) {
            __half2 pa = __hadd2(*(__half2*)&u[k].x, *(__half2*)&u[k + 1].x);
            __half2 pb = __hadd2(*(__half2*)&u[k].y, *(__half2*)&u[k + 1].y);
            float2 fa = __half22float2(pa), fb = __half22float2(pb);
            acc.x += fa.x; acc.y += fa.y; acc.z += fb.x; acc.w += fb.y;
        }
    }
    for (int j2 = je; j2 < jfull; j2++) {        // LCAP overflow: global, rare
        int s = (int)csr[wb + j2] + gbase;
        uint2 u = *(const uint2*)&sh[(size_t)s * 64 + fl * 4];
        float2 f0 = __half22float2(*(__half2*)&u.x);
        float2 f1 = __half22float2(*(__half2*)&u.y);
        acc.x += f0.x; acc.y += f0.y; acc.z += f1.x; acc.w += f1.y;
    }
    uint2 su = *(const uint2*)&sh[(size_t)d * 64 + fl * 4];
    float2 sf0 = __half22float2(*(__half2*)&su.x);
    float2 sf1 = __half22float2(*(__half2*)&su.y);
    float dv = ldv[n];
    // Y row n, feats fl*4..+3 -> LDS (no global Y)
    __half2 lo = __floats2half2_rn((acc.x + sf0.x) * dv, (acc.y + sf0.y) * dv);
    __half2 hi = __floats2half2_rn((acc.z + sf1.x) * dv, (acc.w + sf1.y) * dv);
    uint2 yu; yu.x = *(unsigned*)&lo; yu.y = *(unsigned*)&hi;
    *(uint2*)&Ylds[n * 72 + fl * 4] = yu;
    __syncthreads();
    // ---- G1: X1 = relu(Y @ W1 + b1), wave handles col-tiles wv*2, wv*2+1 ----
    {
        half8 ya[2];
        #pragma unroll
        for (int kc = 0; kc < 2; kc++)
            ya[kc] = *(const half8*)&Ylds[fl * 72 + kc * 32 + sub * 8];
        #pragma unroll
        for (int j = 0; j < 2; j++) {
            const int nt = wv * 2 + j;
            floatx4 a1 = {};
            #pragma unroll
            for (int kc = 0; kc < 2; kc++) {
                half8 bf = *(const half8*)&Wf1[((kc * 8 + nt) * 64 + lane) * 8];
                a1 = __builtin_amdgcn_mfma_f32_16x16x32_f16(ya[kc], bf, a1, 0, 0, 0);
            }
            float bv = b1[nt * 16 + fl];
            #pragma unroll
            for (int reg = 0; reg < 4; reg++) {
                float v = fmaxf(a1[reg] + bv, 0.f);
                X1l[(sub * 4 + reg) * X1S + nt * 16 + fl] = (_Float16)v;
            }
        }
    }
    __syncthreads();
    // ---- G2: gh = dinv * (X1 @ W2), wave handles col-tile wv ----
    {
        floatx4 a2 = {};
        #pragma unroll
        for (int kc = 0; kc < 4; kc++) {
            half8 xa = *(const half8*)&X1l[fl * X1S + kc * 32 + sub * 8];
            half8 bf = *(const half8*)&Wf2[((kc * 4 + wv) * 64 + lane) * 8];
            a2 = __builtin_amdgcn_mfma_f32_16x16x32_f16(xa, bf, a2, 0, 0, 0);
        }
        #pragma unroll
        for (int reg = 0; reg < 4; reg++) {
            int row = sub * 4 + reg;
            float v = a2[reg] * ldv[row];
            gh[(size_t)(n0 + row) * 64 + wv * 16 + fl] = (_Float16)v;
        }
    }
}

// ---------------------------------------------------------------------------
// Pull aggregation (layer 2), NODE-PER-SUB: block = 16 nodes, 4 waves; each
// wave's 4 sub-quads own ONE node; lane accumulates its 8-byte slice
// in-register. Predicated gathers; full-64-lane self-load; compacted store.
// ---------------------------------------------------------------------------
template<bool BIAS_RELU, bool COMPACT_OUT, bool OUT_HALF>
__global__ __launch_bounds__(256) void pull_agg_k(const __half* __restrict__ sh,
        const unsigned short* __restrict__ csr, const int* __restrict__ rowptr,
        const float* __restrict__ dinv, const float* __restrict__ bias,
        void* __restrict__ outv) {
    __shared__ unsigned short lcsr[LCAP];
    __shared__ int lrp[PBN + 1];
    __shared__ float ldv[PBN];
    const int tid = threadIdx.x;
    const int n0 = blockIdx.x * PBN;             // padded node base (no straddle)
    const int g2 = n0 >= NPAD;
    const int gbase = g2 ? NPAD : 0;
    if (tid <= PBN) lrp[tid] = rowptr[n0 + tid];
    if (tid < PBN)  ldv[tid] = dinv[n0 + tid];
    __syncthreads();
    const int wb = lrp[0];
    const int wcnt = min(lrp[PBN] - wb, LCAP);
    for (int i = tid; i < wcnt; i += 256) lcsr[i] = csr[wb + i];
    __syncthreads();
    const int wv = tid >> 6, lane = tid & 63;
    const int sub = lane >> 4, fl = lane & 15;
    const int n = wv * 4 + sub;                  // this lane's node (0..15)
    const int d = n0 + n;
    const int jfull = lrp[n + 1] - wb;
    const int jb = min(lrp[n] - wb, wcnt);
    const int je = min(jfull, wcnt);
    float4 acc = {0.f, 0.f, 0.f, 0.f};
    for (int j = jb; j < je; j += 8) {
        uint2 u[8];
        #pragma unroll
        for (int k = 0; k < 8; k++) {
            uint2 v; v.x = 0u; v.y = 0u;
            int idx = j + k;
            if (idx < je) {                      // sub-uniform guard: no request if off
                int s = (int)lcsr[idx] + gbase;
                v = *(const uint2*)&sh[(size_t)s * 64 + fl * 4];
            }
            u[k] = v;
        }
        #pragma unroll
        for (int k = 0; k < 8; k += 2) {
            __half2 pa = __hadd2(*(__half2*)&u[k].x, *(__half2*)&u[k + 1].x);
            __half2 pb = __hadd2(*(__half2*)&u[k].y, *(__half2*)&u[k + 1].y);
            float2 fa = __half22float2(pa), fb = __half22float2(pb);
            acc.x += fa.x; acc.y += fa.y; acc.z += fb.x; acc.w += fb.y;
        }
    }
    for (int j2 = je; j2 < jfull; j2++) {        // LCAP overflow: global, rare
        int s = (int)csr[wb + j2] + gbase;
        uint2 u = *(const uint2*)&sh[(size_t)s * 64 + fl * 4];
        float2 f0 = __half22float2(*(__half2*)&u.x);
        float2 f1 = __half22float2(*(__half2*)&u.y);
        acc.x += f0.x; acc.y += f0.y; acc.z += f1.x; acc.w += f1.y;
    }
    uint2 su = *(const uint2*)&sh[(size_t)d * 64 + fl * 4];
    float2 sf0 = __half22float2(*(__half2*)&su.x);
    float2 sf1 = __half22float2(*(__half2*)&su.y);
    float dv = ldv[n];
    float4 o;
    o.x = (acc.x + sf0.x) * dv;
    o.y = (acc.y + sf0.y) * dv;
    o.z = (acc.z + sf1.x) * dv;
    o.w = (acc.w + sf1.y) * dv;
    if (BIAS_RELU) {
        float4 bv = *(const float4*)&bias[fl * 4];
        o.x = fmaxf(o.x + bv.x, 0.f);
        o.y = fmaxf(o.y + bv.y, 0.f);
        o.z = fmaxf(o.z + bv.z, 0.f);
        o.w = fmaxf(o.w + bv.w, 0.f);
    }
    if (OUT_HALF) {
        __half2 lo = __floats2half2_rn(o.x, o.y);
        __half2 hi = __floats2half2_rn(o.z, o.w);
        uint2 u2; u2.x = *(unsigned*)&lo; u2.y = *(unsigned*)&hi;
        *(uint2*)&((__half*)outv)[(size_t)d * 64 + fl * 4] = u2;     // padded
    } else {
        int local = d - gbase;
        if (!COMPACT_OUT) {
            *(float4*)&((float*)outv)[(size_t)d * 64 + fl * 4] = o;
        } else if (local < N_NODES) {
            size_t orow = (size_t)(g2 ? N_NODES + local : local);
            floatx4 ov; ov.x = o.x; ov.y = o.y; ov.z = o.z; ov.w = o.w;
            __builtin_nontemporal_store(ov,
                (floatx4*)&((float*)outv)[orow * 64 + fl * 4]);
        }
    }
}

extern "C" void kernel_launch(void* const* d_in, const int* in_sizes, int n_in,
                              void* d_out, int out_size, void* d_ws, size_t ws_size,
                              hipStream_t stream) {
    const float* x1 = (const float*)d_in[0];
    const int*   e1 = (const int*)d_in[1];
    const float* x2 = (const float*)d_in[2];
    const int*   e2 = (const int*)d_in[3];
    const float* W1 = (const float*)d_in[4];
    const float* b1 = (const float*)d_in[5];
    const float* W2 = (const float*)d_in[6];
    const float* b2 = (const float*)d_in[7];
    float* out = (float*)d_out;

    // Workspace (~45 MB), 256 B-aligned chunks.
    char* p = (char*)d_ws;
    auto alloc = [&](size_t bytes) { char* r = p; p += (bytes + 255) & ~(size_t)255; return r; };
    unsigned* bcount = (unsigned*)alloc((size_t)(NBKT * CSTRIDE + CSTRIDE) * 4);
    unsigned* done   = bcount + NBKT * CSTRIDE;    // own cache line
    int*      bexcl  = (int*)alloc(NBKT * 4);
    float*    dinv   = (float*)alloc((size_t)2 * NPAD * 4);
    int*      rowptr = (int*)alloc(((size_t)2 * NPAD + 1) * 4);
    unsigned* bbuf   = (unsigned*)alloc((size_t)NBKT * BCAP * 4);
    unsigned short* csr = (unsigned short*)alloc((size_t)2 * N_EDGES * 2);
    __half*   sxh    = (__half*)alloc((size_t)2 * NPAD * 64 * 2);    // fp16 feats
    _Float16* gh     = (_Float16*)alloc((size_t)2 * NPAD * 64 * 2);  // fused out;
                                   // must NOT alias sxh (pull1g reads sxh while
                                   // writing gh)
    _Float16* Wf1    = (_Float16*)alloc(8192 * 2);
    _Float16* Wf2    = (_Float16*)alloc(8192 * 2);

    // ---- CSR build + dinv + fp16 prescale + W fragment pack (fused) ----
    (void)hipMemsetAsync(bcount, 0, (size_t)(NBKT * CSTRIDE + CSTRIDE) * 4, stream);
    binA_k<<<NEB + 2, 256, 0, stream>>>(e1, e2, W1, W2, bcount, bbuf, Wf1, Wf2, done, bexcl);
    buildB_k<<<NBKT, 256, 0, stream>>>(bcount, bexcl, bbuf, x1, x2, csr, rowptr, dinv, sxh);

    // ---- layer 1 agg + BOTH weight GEMMs fused: gh = fp16(dinv*(relu(Y@W1+b1)@W2)) ----
    pull1g_k<<<2 * NPAD / PBN, 256, 0, stream>>>(
        sxh, csr, rowptr, dinv, Wf1, b1, Wf2, gh);
    // ---- layer 2 agg + epilogue: out = relu(dinv*(sum+self)+b2) ----
    pull_agg_k<true, true, false><<<2 * NPAD / PBN, 256, 0, stream>>>(
        (const __half*)gh, csr, rowptr, dinv, b2, out);
}

// Round 8
// 190.694 us; speedup vs baseline: 1.2079x; 1.0666x over previous
//
#include <hip/hip_runtime.h>
#include <hip/hip_fp16.h>

#define N_NODES 50000
#define N_EDGES 800000
#define NPAD    50176          // 196*256: graph-2 node base, bucket-aligned
#define NBKT    392            // (2*NPAD)/256 buckets of 256 nodes
#define BCAP    6144           // bucket capacity; mean 4082, sigma 64 -> +32 sigma
#define PBN     16             // nodes per pull block (NPAD % PBN == 0)
#define LCAP    1024           // staged csr window cap (mean 256, +48 sigma)
#define X1S     136            // LDS X1 stride (halfs): 272 B rows, 16B-aligned
#define EPB     4096           // measured-best (R3: 2048 worse, R6: 16384 worse)
#define NEB     ((2 * N_EDGES + EPB - 1) / EPB)   // 391 edge blocks
#define CSTRIDE 16             // one atomic counter per 64B line (R5)
#define ATH     1024           // R8: binA threads 256->1024. binA is per-block
                               // latency-chain bound (R6: 4x iters -> 2.7x time);
                               // 4x waves = 4x fewer serial iters per phase.
#define BTH     512            // R8: buildB threads 256->512, same logic.
static_assert(N_NODES < 65536, "u16 CSR requires local node ids < 65536");
static_assert(EPB <= 65536, "u16 sidx requires EPB <= 65536");
// LAYOUT RULE: all intermediate buffers indexed by PADDED gid (g*NPAD + i).
// Compaction to the harness's [2*N_NODES,64] output only at pull-2's store.
// Gather/GEMM feature buffers are fp16; all accumulation fp32 (MFMA C=f32).

typedef _Float16 __attribute__((ext_vector_type(8))) half8;
typedef float    __attribute__((ext_vector_type(4))) floatx4;

// Per-block edge-index stride detection (int64 vs int32): odd 32-bit words of
// little-endian int64 with values < 2^31 are all zero.
__device__ __forceinline__ int detect_stride_block(const int* raw1, int* sflag) {
    int odd = 0;
    for (int i = threadIdx.x; i < 2048; i += blockDim.x) odd |= raw1[2 * i + 1];
    if (threadIdx.x == 0) *sflag = 0;
    __syncthreads();
    if (odd) atomicOr(sflag, 1);
    __syncthreads();
    return *sflag ? 1 : 2;
}

// ---------------------------------------------------------------------------
// Pass A, SINGLE-PASS, NEB edge-blocks x EPB edges, 1024 threads: LDS hist ->
// line-padded global reserve -> guarded 512-H-S scan -> LDS counting sort ->
// coalesced flush. Entry: (dst_in_bucket << 16) | src_local. Blocks NEB/NEB+1
// pack W1/W2 into MFMA B-fragment order. Last-finishing edge block computes
// the bucket-base exclusive scan -> bexcl (device-scope done counter).
// ---------------------------------------------------------------------------
__global__ __launch_bounds__(ATH) void binA_k(const int* __restrict__ raw1,
        const int* __restrict__ raw2, const float* __restrict__ W1,
        const float* __restrict__ W2, unsigned* __restrict__ bcount,
        unsigned* __restrict__ bbuf, _Float16* __restrict__ Wf1,
        _Float16* __restrict__ Wf2, unsigned* __restrict__ done,
        int* __restrict__ bexcl) {
    const int tid = threadIdx.x;
    if (blockIdx.x >= NEB) {                 // fused wprep
        const int wsel = blockIdx.x - NEB;
        const float* W = wsel ? W2 : W1;
        _Float16* Wf = wsel ? Wf2 : Wf1;
        const int M = wsel ? 64 : 128;
        const int NT = M / 16;
        for (int i = tid; i < 8192; i += ATH) {           // 16 frags x 512
            int f = i >> 9, r = i & 511;
            int lane = r >> 3, j = r & 7;
            int kc = f / NT, nt = f % NT;
            int k = kc * 32 + (lane >> 4) * 8 + j;
            int m = nt * 16 + (lane & 15);
            Wf[i] = (_Float16)W[k * M + m];
        }
        return;
    }
    __shared__ unsigned ent[EPB];            // 16 KB
    __shared__ unsigned short ebkt[EPB];     // 8 KB
    __shared__ unsigned short sidx[EPB];     // 8 KB: bucket-sorted entry indices
    __shared__ unsigned hist[NBKT], gofs[NBKT];
    __shared__ int lofs[NBKT], cur[NBKT];
    __shared__ int t2[512];
    __shared__ int sflag;
    const int stride = detect_stride_block(raw1, &sflag);
    for (int b = tid; b < NBKT; b += ATH) hist[b] = 0u;
    __syncthreads();
    const long long e0 = (long long)blockIdx.x * EPB;
    const int scnt = (int)min((long long)EPB, 2LL * N_EDGES - e0);
    #pragma unroll
    for (int it = 0; it < EPB / ATH; it++) {
        int i = it * ATH + tid;
        if (i < scnt) {
            long long e = e0 + i;
            int g2 = e >= N_EDGES;
            const int* raw = g2 ? raw2 : raw1;
            long long el = e - (g2 ? N_EDGES : 0);
            int s = raw[el * stride];
            int d = raw[((long long)N_EDGES + el) * stride];
            int gid = g2 * NPAD + d;
            int bkt = gid >> 8;
            ent[i] = ((unsigned)(gid & 255) << 16) | (unsigned)s;
            ebkt[i] = (unsigned short)bkt;
            atomicAdd(&hist[bkt], 1u);
        }
    }
    __syncthreads();
    // reserve global runs (one counter per cache line)
    if (tid < NBKT) {
        unsigned c = hist[tid];
        gofs[tid] = c ? atomicAdd(&bcount[tid * CSTRIDE], c) : 0u;
    }
    // exclusive scan of hist -> lofs (guarded 512 Hillis-Steele, all threads
    // hit every barrier)
    if (tid < 512) t2[tid] = (tid < NBKT) ? (int)hist[tid] : 0;
    __syncthreads();
    #pragma unroll
    for (int off = 1; off < 512; off <<= 1) {
        int a0 = (tid < 512 && tid >= off) ? t2[tid - off] : 0;
        __syncthreads();
        if (tid < 512) t2[tid] += a0;
        __syncthreads();
    }
    if (tid < NBKT) { int l = t2[tid] - (int)hist[tid]; lofs[tid] = l; cur[tid] = l; }
    __syncthreads();
    // place entry indices in bucket-sorted order
    #pragma unroll
    for (int it = 0; it < EPB / ATH; it++) {
        int i = it * ATH + tid;
        if (i < scnt) {
            int bkt = (int)ebkt[i];
            int p = atomicAdd(&cur[bkt], 1);
            sidx[p] = (unsigned short)i;
        }
    }
    __syncthreads();
    // coalesced flush: consecutive i within a bucket run -> consecutive addrs
    #pragma unroll
    for (int it = 0; it < EPB / ATH; it++) {
        int i = it * ATH + tid;
        if (i < scnt) {
            int e = (int)sidx[i];
            int bkt = (int)ebkt[e];
            unsigned pos = gofs[bkt] + (unsigned)(i - lofs[bkt]);
            if (pos < BCAP) bbuf[(size_t)bkt * BCAP + pos] = ent[e];
        }
    }
    // ---- last-finisher computes exclusive bucket scan (no block ever waits) ----
    __syncthreads();
    __shared__ int lastf;
    if (tid == 0) {
        __threadfence();
        lastf = (atomicAdd(done, 1u) == (unsigned)(NEB - 1)) ? 1 : 0;
    }
    __syncthreads();
    if (lastf) {
        int v0 = (tid < NBKT) ? (int)atomicAdd(&bcount[tid * CSTRIDE], 0u) : 0;
        if (tid < 512) t2[tid] = v0;
        __syncthreads();
        #pragma unroll
        for (int off = 1; off < 512; off <<= 1) {
            int a0 = (tid < 512 && tid >= off) ? t2[tid - off] : 0;
            __syncthreads();
            if (tid < 512) t2[tid] += a0;
            __syncthreads();
        }
        if (tid < NBKT) bexcl[tid] = t2[tid] - v0;
    }
}

// ---------------------------------------------------------------------------
// Pass B, 512 threads: one block per bucket. CSR base read from bexcl;
// per-node degree + rowptr + dinv (wave-scan over waves 0-3); LDS-cursor CSR
// scatter; fused fp16 prescale sxh = dinv * x.
// ---------------------------------------------------------------------------
__global__ __launch_bounds__(BTH) void buildB_k(const unsigned* __restrict__ bcount,
        const int* __restrict__ bexcl, const unsigned* __restrict__ bbuf,
        const float* __restrict__ x1, const float* __restrict__ x2,
        unsigned short* __restrict__ csr, int* __restrict__ rowptr,
        float* __restrict__ dinv, __half* __restrict__ sxh) {
    __shared__ unsigned ent[BCAP];
    __shared__ int deg[256], cur[256];
    __shared__ int wsum[4];
    __shared__ float sdinv[256];
    const int b = blockIdx.x, tid = threadIdx.x;
    const int cnt = min((int)bcount[b * CSTRIDE], BCAP);
    const int eb = bexcl[b];
    for (int i = tid; i < cnt; i += BTH) ent[i] = bbuf[(size_t)b * BCAP + i];
    if (tid < 256) deg[tid] = 0;
    __syncthreads();
    for (int i = tid; i < cnt; i += BTH) atomicAdd(&deg[ent[i] >> 16], 1);
    __syncthreads();
    if (tid < 256) {                             // waves 0-3: scan + rowptr + dinv
        const int v = deg[tid];
        const int lane = tid & 63, w = tid >> 6;
        int x = v;                               // wave-inclusive scan
        #pragma unroll
        for (int off = 1; off < 64; off <<= 1) {
            int y = __shfl_up(x, off);
            if (lane >= off) x += y;
        }
        if (lane == 63) wsum[w] = x;
        // intra-wave done; cross-wave prefix needs wsum visible -> barrier below
        cur[tid] = x - v;                        // provisional (wave-local excl)
        const int gid = b * 256 + tid;
        float dv = rsqrtf((float)v + 1.0f);      // +1 self-loop
        dinv[gid] = dv;
        sdinv[tid] = dv;
    }
    __syncthreads();
    if (tid < 256) {
        const int v = deg[tid];
        const int w = tid >> 6;
        int wpre = 0;
        #pragma unroll
        for (int i = 0; i < 4; i++) wpre += (i < w) ? wsum[i] : 0;
        const int excl = cur[tid] + wpre;
        cur[tid] = excl;
        const int gid = b * 256 + tid;
        rowptr[gid] = eb + excl;
        if (b == NBKT - 1 && tid == 255) rowptr[2 * NPAD] = eb + excl + v;
    }
    __syncthreads();
    for (int i = tid; i < cnt; i += BTH) {
        unsigned p = ent[i];
        int pos = atomicAdd(&cur[p >> 16], 1);
        csr[eb + pos] = (unsigned short)(p & 0xFFFFu);
    }
    const int g2 = (b * 256) >= NPAD;
    const float* x0 = g2 ? x2 : x1;
    const int lbase = b * 256 - (g2 ? NPAD : 0);
    for (int i = tid; i < 256 * 16; i += BTH) {
        int n = i >> 4, q = i & 15;
        int local = lbase + n;
        __half2 lo = __floats2half2_rn(0.f, 0.f), hi = lo;
        if (local < N_NODES) {
            float4 vx = *(const float4*)&x0[((size_t)local * 16 + q) * 4];
            float dn = sdinv[n];
            lo = __floats2half2_rn(vx.x * dn, vx.y * dn);
            hi = __floats2half2_rn(vx.z * dn, vx.w * dn);
        }
        uint2 u; u.x = *(unsigned*)&lo; u.y = *(unsigned*)&hi;
        *(uint2*)&sxh[(size_t)(b * 256 + n) * 64 + q * 4] = u;
    }
}

// ---------------------------------------------------------------------------
// FUSED pull-1 + both weight GEMMs (R7-verified): Y -> LDS (stride 72),
// G1 = relu(Y@W1+b1) -> LDS X1 (stride 136), G2 = dinv*(X1@W2) -> gh.
// 32 MFMAs / block across 4 waves. gh MUST NOT alias sxh.
// ---------------------------------------------------------------------------
__global__ __launch_bounds__(256) void pull1g_k(const __half* __restrict__ sh,
        const unsigned short* __restrict__ csr, const int* __restrict__ rowptr,
        const float* __restrict__ dinv, const _Float16* __restrict__ Wf1,
        const float* __restrict__ b1, const _Float16* __restrict__ Wf2,
        _Float16* __restrict__ gh) {
    __shared__ unsigned short lcsr[LCAP];
    __shared__ int lrp[PBN + 1];
    __shared__ float ldv[PBN];
    __shared__ _Float16 Ylds[16 * 72];           // 2.3 KB, row stride 144 B
    __shared__ _Float16 X1l[16 * X1S];           // 4.4 KB
    const int tid = threadIdx.x;
    const int n0 = blockIdx.x * PBN;             // padded node base (no straddle)
    const int g2 = n0 >= NPAD;
    const int gbase = g2 ? NPAD : 0;
    if (tid <= PBN) lrp[tid] = rowptr[n0 + tid];
    if (tid < PBN)  ldv[tid] = dinv[n0 + tid];
    __syncthreads();
    const int wb = lrp[0];
    const int wcnt = min(lrp[PBN] - wb, LCAP);
    for (int i = tid; i < wcnt; i += 256) lcsr[i] = csr[wb + i];
    __syncthreads();
    const int wv = tid >> 6, lane = tid & 63;
    const int sub = lane >> 4, fl = lane & 15;   // sub == MFMA quad, fl == col
    const int n = wv * 4 + sub;                  // this lane's node (0..15)
    const int d = n0 + n;
    const int jfull = lrp[n + 1] - wb;
    const int jb = min(lrp[n] - wb, wcnt);
    const int je = min(jfull, wcnt);
    float4 acc = {0.f, 0.f, 0.f, 0.f};
    for (int j = jb; j < je; j += 8) {
        uint2 u[8];
        #pragma unroll
        for (int k = 0; k < 8; k++) {
            uint2 v; v.x = 0u; v.y = 0u;
            int idx = j + k;
            if (idx < je) {
                int s = (int)lcsr[idx] + gbase;
                v = *(const uint2*)&sh[(size_t)s * 64 + fl * 4];
            }
            u[k] = v;
        }
        #pragma unroll
        for (int k = 0; k < 8; k += 2) {
            __half2 pa = __hadd2(*(__half2*)&u[k].x, *(__half2*)&u[k + 1].x);
            __half2 pb = __hadd2(*(__half2*)&u[k].y, *(__half2*)&u[k + 1].y);
            float2 fa = __half22float2(pa), fb = __half22float2(pb);
            acc.x += fa.x; acc.y += fa.y; acc.z += fb.x; acc.w += fb.y;
        }
    }
    for (int j2 = je; j2 < jfull; j2++) {        // LCAP overflow: global, rare
        int s = (int)csr[wb + j2] + gbase;
        uint2 u = *(const uint2*)&sh[(size_t)s * 64 + fl * 4];
        float2 f0 = __half22float2(*(__half2*)&u.x);
        float2 f1 = __half22float2(*(__half2*)&u.y);
        acc.x += f0.x; acc.y += f0.y; acc.z += f1.x; acc.w += f1.y;
    }
    uint2 su = *(const uint2*)&sh[(size_t)d * 64 + fl * 4];
    float2 sf0 = __half22float2(*(__half2*)&su.x);
    float2 sf1 = __half22float2(*(__half2*)&su.y);
    float dv = ldv[n];
    // Y row n, feats fl*4..+3 -> LDS (no global Y)
    __half2 lo = __floats2half2_rn((acc.x + sf0.x) * dv, (acc.y + sf0.y) * dv);
    __half2 hi = __floats2half2_rn((acc.z + sf1.x) * dv, (acc.w + sf1.y) * dv);
    uint2 yu; yu.x = *(unsigned*)&lo; yu.y = *(unsigned*)&hi;
    *(uint2*)&Ylds[n * 72 + fl * 4] = yu;
    __syncthreads();
    // ---- G1: X1 = relu(Y @ W1 + b1), wave handles col-tiles wv*2, wv*2+1 ----
    {
        half8 ya[2];
        #pragma unroll
        for (int kc = 0; kc < 2; kc++)
            ya[kc] = *(const half8*)&Ylds[fl * 72 + kc * 32 + sub * 8];
        #pragma unroll
        for (int j = 0; j < 2; j++) {
            const int nt = wv * 2 + j;
            floatx4 a1 = {};
            #pragma unroll
            for (int kc = 0; kc < 2; kc++) {
                half8 bf = *(const half8*)&Wf1[((kc * 8 + nt) * 64 + lane) * 8];
                a1 = __builtin_amdgcn_mfma_f32_16x16x32_f16(ya[kc], bf, a1, 0, 0, 0);
            }
            float bv = b1[nt * 16 + fl];
            #pragma unroll
            for (int reg = 0; reg < 4; reg++) {
                float v = fmaxf(a1[reg] + bv, 0.f);
                X1l[(sub * 4 + reg) * X1S + nt * 16 + fl] = (_Float16)v;
            }
        }
    }
    __syncthreads();
    // ---- G2: gh = dinv * (X1 @ W2), wave handles col-tile wv ----
    {
        floatx4 a2 = {};
        #pragma unroll
        for (int kc = 0; kc < 4; kc++) {
            half8 xa = *(const half8*)&X1l[fl * X1S + kc * 32 + sub * 8];
            half8 bf = *(const half8*)&Wf2[((kc * 4 + wv) * 64 + lane) * 8];
            a2 = __builtin_amdgcn_mfma_f32_16x16x32_f16(xa, bf, a2, 0, 0, 0);
        }
        #pragma unroll
        for (int reg = 0; reg < 4; reg++) {
            int row = sub * 4 + reg;
            float v = a2[reg] * ldv[row];
            gh[(size_t)(n0 + row) * 64 + wv * 16 + fl] = (_Float16)v;
        }
    }
}

// ---------------------------------------------------------------------------
// Pull aggregation (layer 2), NODE-PER-SUB: block = 16 nodes, 4 waves; each
// wave's 4 sub-quads own ONE node; lane accumulates its 8-byte slice
// in-register. Predicated gathers; full-64-lane self-load; compacted store.
// ---------------------------------------------------------------------------
template<bool BIAS_RELU, bool COMPACT_OUT, bool OUT_HALF>
__global__ __launch_bounds__(256) void pull_agg_k(const __half* __restrict__ sh,
        const unsigned short* __restrict__ csr, const int* __restrict__ rowptr,
        const float* __restrict__ dinv, const float* __restrict__ bias,
        void* __restrict__ outv) {
    __shared__ unsigned short lcsr[LCAP];
    __shared__ int lrp[PBN + 1];
    __shared__ float ldv[PBN];
    const int tid = threadIdx.x;
    const int n0 = blockIdx.x * PBN;             // padded node base (no straddle)
    const int g2 = n0 >= NPAD;
    const int gbase = g2 ? NPAD : 0;
    if (tid <= PBN) lrp[tid] = rowptr[n0 + tid];
    if (tid < PBN)  ldv[tid] = dinv[n0 + tid];
    __syncthreads();
    const int wb = lrp[0];
    const int wcnt = min(lrp[PBN] - wb, LCAP);
    for (int i = tid; i < wcnt; i += 256) lcsr[i] = csr[wb + i];
    __syncthreads();
    const int wv = tid >> 6, lane = tid & 63;
    const int sub = lane >> 4, fl = lane & 15;
    const int n = wv * 4 + sub;                  // this lane's node (0..15)
    const int d = n0 + n;
    const int jfull = lrp[n + 1] - wb;
    const int jb = min(lrp[n] - wb, wcnt);
    const int je = min(jfull, wcnt);
    float4 acc = {0.f, 0.f, 0.f, 0.f};
    for (int j = jb; j < je; j += 8) {
        uint2 u[8];
        #pragma unroll
        for (int k = 0; k < 8; k++) {
            uint2 v; v.x = 0u; v.y = 0u;
            int idx = j + k;
            if (idx < je) {                      // sub-uniform guard: no request if off
                int s = (int)lcsr[idx] + gbase;
                v = *(const uint2*)&sh[(size_t)s * 64 + fl * 4];
            }
            u[k] = v;
        }
        #pragma unroll
        for (int k = 0; k < 8; k += 2) {
            __half2 pa = __hadd2(*(__half2*)&u[k].x, *(__half2*)&u[k + 1].x);
            __half2 pb = __hadd2(*(__half2*)&u[k].y, *(__half2*)&u[k + 1].y);
            float2 fa = __half22float2(pa), fb = __half22float2(pb);
            acc.x += fa.x; acc.y += fa.y; acc.z += fb.x; acc.w += fb.y;
        }
    }
    for (int j2 = je; j2 < jfull; j2++) {        // LCAP overflow: global, rare
        int s = (int)csr[wb + j2] + gbase;
        uint2 u = *(const uint2*)&sh[(size_t)s * 64 + fl * 4];
        float2 f0 = __half22float2(*(__half2*)&u.x);
        float2 f1 = __half22float2(*(__half2*)&u.y);
        acc.x += f0.x; acc.y += f0.y; acc.z += f1.x; acc.w += f1.y;
    }
    uint2 su = *(const uint2*)&sh[(size_t)d * 64 + fl * 4];
    float2 sf0 = __half22float2(*(__half2*)&su.x);
    float2 sf1 = __half22float2(*(__half2*)&su.y);
    float dv = ldv[n];
    float4 o;
    o.x = (acc.x + sf0.x) * dv;
    o.y = (acc.y + sf0.y) * dv;
    o.z = (acc.z + sf1.x) * dv;
    o.w = (acc.w + sf1.y) * dv;
    if (BIAS_RELU) {
        float4 bv = *(const float4*)&bias[fl * 4];
        o.x = fmaxf(o.x + bv.x, 0.f);
        o.y = fmaxf(o.y + bv.y, 0.f);
        o.z = fmaxf(o.z + bv.z, 0.f);
        o.w = fmaxf(o.w + bv.w, 0.f);
    }
    if (OUT_HALF) {
        __half2 lo = __floats2half2_rn(o.x, o.y);
        __half2 hi = __floats2half2_rn(o.z, o.w);
        uint2 u2; u2.x = *(unsigned*)&lo; u2.y = *(unsigned*)&hi;
        *(uint2*)&((__half*)outv)[(size_t)d * 64 + fl * 4] = u2;     // padded
    } else {
        int local = d - gbase;
        if (!COMPACT_OUT) {
            *(float4*)&((float*)outv)[(size_t)d * 64 + fl * 4] = o;
        } else if (local < N_NODES) {
            size_t orow = (size_t)(g2 ? N_NODES + local : local);
            floatx4 ov; ov.x = o.x; ov.y = o.y; ov.z = o.z; ov.w = o.w;
            __builtin_nontemporal_store(ov,
                (floatx4*)&((float*)outv)[orow * 64 + fl * 4]);
        }
    }
}

extern "C" void kernel_launch(void* const* d_in, const int* in_sizes, int n_in,
                              void* d_out, int out_size, void* d_ws, size_t ws_size,
                              hipStream_t stream) {
    const float* x1 = (const float*)d_in[0];
    const int*   e1 = (const int*)d_in[1];
    const float* x2 = (const float*)d_in[2];
    const int*   e2 = (const int*)d_in[3];
    const float* W1 = (const float*)d_in[4];
    const float* b1 = (const float*)d_in[5];
    const float* W2 = (const float*)d_in[6];
    const float* b2 = (const float*)d_in[7];
    float* out = (float*)d_out;

    // Workspace (~45 MB), 256 B-aligned chunks.
    char* p = (char*)d_ws;
    auto alloc = [&](size_t bytes) { char* r = p; p += (bytes + 255) & ~(size_t)255; return r; };
    unsigned* bcount = (unsigned*)alloc((size_t)(NBKT * CSTRIDE + CSTRIDE) * 4);
    unsigned* done   = bcount + NBKT * CSTRIDE;    // own cache line
    int*      bexcl  = (int*)alloc(NBKT * 4);
    float*    dinv   = (float*)alloc((size_t)2 * NPAD * 4);
    int*      rowptr = (int*)alloc(((size_t)2 * NPAD + 1) * 4);
    unsigned* bbuf   = (unsigned*)alloc((size_t)NBKT * BCAP * 4);
    unsigned short* csr = (unsigned short*)alloc((size_t)2 * N_EDGES * 2);
    __half*   sxh    = (__half*)alloc((size_t)2 * NPAD * 64 * 2);    // fp16 feats
    _Float16* gh     = (_Float16*)alloc((size_t)2 * NPAD * 64 * 2);  // fused out;
                                   // must NOT alias sxh (pull1g reads sxh while
                                   // writing gh)
    _Float16* Wf1    = (_Float16*)alloc(8192 * 2);
    _Float16* Wf2    = (_Float16*)alloc(8192 * 2);

    // ---- CSR build + dinv + fp16 prescale + W fragment pack (fused) ----
    (void)hipMemsetAsync(bcount, 0, (size_t)(NBKT * CSTRIDE + CSTRIDE) * 4, stream);
    binA_k<<<NEB + 2, ATH, 0, stream>>>(e1, e2, W1, W2, bcount, bbuf, Wf1, Wf2, done, bexcl);
    buildB_k<<<NBKT, BTH, 0, stream>>>(bcount, bexcl, bbuf, x1, x2, csr, rowptr, dinv, sxh);

    // ---- layer 1 agg + BOTH weight GEMMs fused: gh = fp16(dinv*(relu(Y@W1+b1)@W2)) ----
    pull1g_k<<<2 * NPAD / PBN, 256, 0, stream>>>(
        sxh, csr, rowptr, dinv, Wf1, b1, Wf2, gh);
    // ---- layer 2 agg + epilogue: out = relu(dinv*(sum+self)+b2) ----
    pull_agg_k<true, true, false><<<2 * NPAD / PBN, 256, 0, stream>>>(
        (const __half*)gh, csr, rowptr, dinv, b2, out);
}

// Round 9
// 181.606 us; speedup vs baseline: 1.2684x; 1.0500x over previous
//
#include <hip/hip_runtime.h>
#include <hip/hip_fp16.h>

#define N_NODES 50000
#define N_EDGES 800000
#define NPAD    50176          // 196*256: graph-2 node base, bucket-aligned
#define NBKT    392            // (2*NPAD)/256 buckets of 256 nodes
#define BCAP    6144           // bucket capacity; mean 4082, sigma 64 -> +32 sigma
#define PBN     16             // nodes per pull block (NPAD % PBN == 0)
#define LCAP    1024           // staged csr window cap (mean 256, +48 sigma)
#define X1S     136            // LDS X1 stride (halfs): 272 B rows, 16B-aligned
#define EPB     4096           // measured-best (R3: 2048 worse, R6: 16384 worse)
#define NEB     ((2 * N_EDGES + EPB - 1) / EPB)   // 391 edge blocks
#define ATH     1024           // R8-verified: binA wide block (latency-chain)
#define BTH     512            // R8-verified: buildB wide block
static_assert(N_NODES < 65536, "u16 CSR requires local node ids < 65536");
static_assert(EPB <= 65536, "u16 sidx/lofsM requires EPB <= 65536");
static_assert(NEB <= BTH, "buildB segment scan assumes one segment per thread");
// R9: ZERO-GLOBAL-ATOMIC binning. R5/R6/R8 triangulated binA's floor to the
// device-atomic reserve chain (391 serialized RMWs/word ~20us). Replaced by
// deterministic placement: block b flushes bucket-sorted entries CONTIGUOUSLY
// to blkbuf[b*EPB..] (coalesced stream) + writes offset row lofsM[b][*]; CSR
// uses fixed per-bucket regions (eb = k*BCAP) so no cross-bucket scan, no
// done-counter, no memset. rowptr -> per-node {start,end} int2 (bucket-end
// gaps harmless). buildB gathers its bucket from 391 segments.
// LAYOUT RULE: all intermediate buffers indexed by PADDED gid (g*NPAD + i).
// Gather/GEMM feature buffers are fp16; all accumulation fp32 (MFMA C=f32).

typedef _Float16 __attribute__((ext_vector_type(8))) half8;
typedef float    __attribute__((ext_vector_type(4))) floatx4;

// Per-block edge-index stride detection (int64 vs int32): odd 32-bit words of
// little-endian int64 with values < 2^31 are all zero.
__device__ __forceinline__ int detect_stride_block(const int* raw1, int* sflag) {
    int odd = 0;
    for (int i = threadIdx.x; i < 2048; i += blockDim.x) odd |= raw1[2 * i + 1];
    if (threadIdx.x == 0) *sflag = 0;
    __syncthreads();
    if (odd) atomicOr(sflag, 1);
    __syncthreads();
    return *sflag ? 1 : 2;
}

// ---------------------------------------------------------------------------
// Pass A, NEB edge-blocks x EPB edges, 1024 threads, NO GLOBAL ATOMICS:
// stage + LDS hist -> guarded 512-H-S scan -> LDS counting sort -> contiguous
// coalesced flush to blkbuf[b*EPB..] + lofsM row (u16 offsets, 393/block).
// Entry: (dst_in_bucket << 16) | src_local. Blocks NEB/NEB+1 pack W1/W2.
// ---------------------------------------------------------------------------
__global__ __launch_bounds__(ATH) void binA_k(const int* __restrict__ raw1,
        const int* __restrict__ raw2, const float* __restrict__ W1,
        const float* __restrict__ W2, unsigned* __restrict__ blkbuf,
        unsigned short* __restrict__ lofsM, _Float16* __restrict__ Wf1,
        _Float16* __restrict__ Wf2) {
    const int tid = threadIdx.x;
    if (blockIdx.x >= NEB) {                 // fused wprep
        const int wsel = blockIdx.x - NEB;
        const float* W = wsel ? W2 : W1;
        _Float16* Wf = wsel ? Wf2 : Wf1;
        const int M = wsel ? 64 : 128;
        const int NT = M / 16;
        for (int i = tid; i < 8192; i += ATH) {           // 16 frags x 512
            int f = i >> 9, r = i & 511;
            int lane = r >> 3, j = r & 7;
            int kc = f / NT, nt = f % NT;
            int k = kc * 32 + (lane >> 4) * 8 + j;
            int m = nt * 16 + (lane & 15);
            Wf[i] = (_Float16)W[k * M + m];
        }
        return;
    }
    __shared__ unsigned ent[EPB];            // 16 KB
    __shared__ unsigned short ebkt[EPB];     // 8 KB
    __shared__ unsigned short sidx[EPB];     // 8 KB: bucket-sorted entry indices
    __shared__ unsigned hist[NBKT];
    __shared__ int lofs[NBKT], cur[NBKT];
    __shared__ int t2[512];
    __shared__ int sflag;
    const int stride = detect_stride_block(raw1, &sflag);
    for (int b = tid; b < NBKT; b += ATH) hist[b] = 0u;
    __syncthreads();
    const long long e0 = (long long)blockIdx.x * EPB;
    const int scnt = (int)min((long long)EPB, 2LL * N_EDGES - e0);
    #pragma unroll
    for (int it = 0; it < EPB / ATH; it++) {
        int i = it * ATH + tid;
        if (i < scnt) {
            long long e = e0 + i;
            int g2 = e >= N_EDGES;
            const int* raw = g2 ? raw2 : raw1;
            long long el = e - (g2 ? N_EDGES : 0);
            int s = raw[el * stride];
            int d = raw[((long long)N_EDGES + el) * stride];
            int gid = g2 * NPAD + d;
            int bkt = gid >> 8;
            ent[i] = ((unsigned)(gid & 255) << 16) | (unsigned)s;
            ebkt[i] = (unsigned short)bkt;
            atomicAdd(&hist[bkt], 1u);
        }
    }
    __syncthreads();
    // exclusive scan of hist -> lofs (guarded 512 Hillis-Steele) + lofsM row
    if (tid < 512) t2[tid] = (tid < NBKT) ? (int)hist[tid] : 0;
    __syncthreads();
    #pragma unroll
    for (int off = 1; off < 512; off <<= 1) {
        int a0 = (tid < 512 && tid >= off) ? t2[tid - off] : 0;
        __syncthreads();
        if (tid < 512) t2[tid] += a0;
        __syncthreads();
    }
    if (tid < NBKT) {
        int l = t2[tid] - (int)hist[tid];
        lofs[tid] = l; cur[tid] = l;
        lofsM[(size_t)blockIdx.x * (NBKT + 1) + tid] = (unsigned short)l;
    }
    if (tid == 0)
        lofsM[(size_t)blockIdx.x * (NBKT + 1) + NBKT] = (unsigned short)scnt;
    __syncthreads();
    // place entry indices in bucket-sorted order (LDS cursors)
    #pragma unroll
    for (int it = 0; it < EPB / ATH; it++) {
        int i = it * ATH + tid;
        if (i < scnt) {
            int bkt = (int)ebkt[i];
            int p = atomicAdd(&cur[bkt], 1);
            sidx[p] = (unsigned short)i;
        }
    }
    __syncthreads();
    // contiguous coalesced flush: blkbuf[b*EPB + i], i = sorted position
    #pragma unroll
    for (int it = 0; it < EPB / ATH; it++) {
        int i = it * ATH + tid;
        if (i < scnt)
            blkbuf[(size_t)blockIdx.x * EPB + i] = ent[(int)sidx[i]];
    }
}

// ---------------------------------------------------------------------------
// Pass B, 512 threads, one block per bucket k: gather the bucket's entries
// from NEB per-block segments (block-wide scan of segment counts -> LDS
// placement); per-node degree + rp2{start,end} + dinv; LDS-cursor CSR
// scatter into fixed region csr[k*BCAP..]; fused fp16 prescale.
// ---------------------------------------------------------------------------
__global__ __launch_bounds__(BTH) void buildB_k(const unsigned short* __restrict__ lofsM,
        const unsigned* __restrict__ blkbuf, const float* __restrict__ x1,
        const float* __restrict__ x2, unsigned short* __restrict__ csr,
        int2* __restrict__ rp2, float* __restrict__ dinv,
        __half* __restrict__ sxh) {
    __shared__ unsigned ent[BCAP];
    __shared__ int deg[256], cur[256];
    __shared__ int wsum8[8], wsum4[4];
    __shared__ int total_s;
    __shared__ float sdinv[256];
    const int k = blockIdx.x, tid = threadIdx.x;
    const int lane = tid & 63, w = tid >> 6;
    // segment sizes: thread t owns source block t
    int s0 = 0, sc = 0;
    if (tid < NEB) {
        s0 = (int)lofsM[(size_t)tid * (NBKT + 1) + k];
        sc = (int)lofsM[(size_t)tid * (NBKT + 1) + k + 1] - s0;
    }
    // block-wide exclusive scan of sc (8 wave scans + cross-wave prefix)
    int x = sc;
    #pragma unroll
    for (int off = 1; off < 64; off <<= 1) {
        int y = __shfl_up(x, off);
        if (lane >= off) x += y;
    }
    if (lane == 63) wsum8[w] = x;
    if (tid < 256) deg[tid] = 0;
    __syncthreads();
    int wpre = 0;
    #pragma unroll
    for (int i = 0; i < 8; i++) wpre += (i < w) ? wsum8[i] : 0;
    const int incl = x + wpre;
    const int ofs = incl - sc;
    if (tid == BTH - 1) total_s = incl;          // last thread holds the total
    __syncthreads();
    const int cnt = min(total_s, BCAP);
    // copy segments into ent (mean ~10.5 u32 per source block)
    if (sc > 0) {
        const unsigned* src = &blkbuf[(size_t)tid * EPB + s0];
        for (int i = 0; i < sc; i++) {
            int p = ofs + i;
            if (p < BCAP) ent[p] = src[i];
        }
    }
    __syncthreads();
    for (int i = tid; i < cnt; i += BTH) atomicAdd(&deg[ent[i] >> 16], 1);
    __syncthreads();
    if (tid < 256) {                             // waves 0-3: node scan
        const int v = deg[tid];
        int y = v;
        #pragma unroll
        for (int off = 1; off < 64; off <<= 1) {
            int z = __shfl_up(y, off);
            if (lane >= off) y += z;
        }
        if (lane == 63) wsum4[w] = y;
        cur[tid] = y - v;                        // wave-local exclusive
        const int gid = k * 256 + tid;
        float dv = rsqrtf((float)v + 1.0f);      // +1 self-loop
        dinv[gid] = dv;
        sdinv[tid] = dv;
    }
    __syncthreads();
    if (tid < 256) {
        const int v = deg[tid];
        int wp = 0;
        #pragma unroll
        for (int i = 0; i < 4; i++) wp += (i < w) ? wsum4[i] : 0;
        const int excl = cur[tid] + wp;
        cur[tid] = excl;
        const int gid = k * 256 + tid;
        int st = k * BCAP + excl;
        rp2[gid] = make_int2(st, st + v);
    }
    __syncthreads();
    for (int i = tid; i < cnt; i += BTH) {
        unsigned p = ent[i];
        int pos = atomicAdd(&cur[p >> 16], 1);   // pos < cnt <= BCAP
        csr[(size_t)k * BCAP + pos] = (unsigned short)(p & 0xFFFFu);
    }
    const int g2 = (k * 256) >= NPAD;
    const float* x0 = g2 ? x2 : x1;
    const int lbase = k * 256 - (g2 ? NPAD : 0);
    for (int i = tid; i < 256 * 16; i += BTH) {
        int n = i >> 4, q = i & 15;
        int local = lbase + n;
        __half2 lo = __floats2half2_rn(0.f, 0.f), hi = lo;
        if (local < N_NODES) {
            float4 vx = *(const float4*)&x0[((size_t)local * 16 + q) * 4];
            float dn = sdinv[n];
            lo = __floats2half2_rn(vx.x * dn, vx.y * dn);
            hi = __floats2half2_rn(vx.z * dn, vx.w * dn);
        }
        uint2 u; u.x = *(unsigned*)&lo; u.y = *(unsigned*)&hi;
        *(uint2*)&sxh[(size_t)(k * 256 + n) * 64 + q * 4] = u;
    }
}

// ---------------------------------------------------------------------------
// FUSED pull-1 + both weight GEMMs (R7-verified): Y -> LDS (stride 72),
// G1 = relu(Y@W1+b1) -> LDS X1 (stride 136), G2 = dinv*(X1@W2) -> gh.
// 32 MFMAs / block across 4 waves. gh MUST NOT alias sxh. rp2 = {start,end}.
// ---------------------------------------------------------------------------
__global__ __launch_bounds__(256) void pull1g_k(const __half* __restrict__ sh,
        const unsigned short* __restrict__ csr, const int2* __restrict__ rp2,
        const float* __restrict__ dinv, const _Float16* __restrict__ Wf1,
        const float* __restrict__ b1, const _Float16* __restrict__ Wf2,
        _Float16* __restrict__ gh) {
    __shared__ unsigned short lcsr[LCAP];
    __shared__ int lrs[PBN], lre[PBN];
    __shared__ float ldv[PBN];
    __shared__ _Float16 Ylds[16 * 72];           // 2.3 KB, row stride 144 B
    __shared__ _Float16 X1l[16 * X1S];           // 4.4 KB
    const int tid = threadIdx.x;
    const int n0 = blockIdx.x * PBN;             // padded node base (no straddle)
    const int g2 = n0 >= NPAD;
    const int gbase = g2 ? NPAD : 0;
    if (tid < PBN) {
        int2 r = rp2[n0 + tid];
        lrs[tid] = r.x; lre[tid] = r.y;
        ldv[tid] = dinv[n0 + tid];
    }
    __syncthreads();
    const int wb = lrs[0];
    const int wcnt = min(lre[PBN - 1] - wb, LCAP);   // rows contiguous in bucket
    for (int i = tid; i < wcnt; i += 256) lcsr[i] = csr[wb + i];
    __syncthreads();
    const int wv = tid >> 6, lane = tid & 63;
    const int sub = lane >> 4, fl = lane & 15;   // sub == MFMA quad, fl == col
    const int n = wv * 4 + sub;                  // this lane's node (0..15)
    const int d = n0 + n;
    const int jfull = lre[n] - wb;
    const int jb = min(lrs[n] - wb, wcnt);
    const int je = min(jfull, wcnt);
    float4 acc = {0.f, 0.f, 0.f, 0.f};
    for (int j = jb; j < je; j += 8) {
        uint2 u[8];
        #pragma unroll
        for (int k = 0; k < 8; k++) {
            uint2 v; v.x = 0u; v.y = 0u;
            int idx = j + k;
            if (idx < je) {
                int s = (int)lcsr[idx] + gbase;
                v = *(const uint2*)&sh[(size_t)s * 64 + fl * 4];
            }
            u[k] = v;
        }
        #pragma unroll
        for (int k = 0; k < 8; k += 2) {
            __half2 pa = __hadd2(*(__half2*)&u[k].x, *(__half2*)&u[k + 1].x);
            __half2 pb = __hadd2(*(__half2*)&u[k].y, *(__half2*)&u[k + 1].y);
            float2 fa = __half22float2(pa), fb = __half22float2(pb);
            acc.x += fa.x; acc.y += fa.y; acc.z += fb.x; acc.w += fb.y;
        }
    }
    for (int j2 = je; j2 < jfull; j2++) {        // LCAP overflow: global, rare
        int s = (int)csr[wb + j2] + gbase;
        uint2 u = *(const uint2*)&sh[(size_t)s * 64 + fl * 4];
        float2 f0 = __half22float2(*(__half2*)&u.x);
        float2 f1 = __half22float2(*(__half2*)&u.y);
        acc.x += f0.x; acc.y += f0.y; acc.z += f1.x; acc.w += f1.y;
    }
    uint2 su = *(const uint2*)&sh[(size_t)d * 64 + fl * 4];
    float2 sf0 = __half22float2(*(__half2*)&su.x);
    float2 sf1 = __half22float2(*(__half2*)&su.y);
    float dv = ldv[n];
    // Y row n, feats fl*4..+3 -> LDS (no global Y)
    __half2 lo = __floats2half2_rn((acc.x + sf0.x) * dv, (acc.y + sf0.y) * dv);
    __half2 hi = __floats2half2_rn((acc.z + sf1.x) * dv, (acc.w + sf1.y) * dv);
    uint2 yu; yu.x = *(unsigned*)&lo; yu.y = *(unsigned*)&hi;
    *(uint2*)&Ylds[n * 72 + fl * 4] = yu;
    __syncthreads();
    // ---- G1: X1 = relu(Y @ W1 + b1), wave handles col-tiles wv*2, wv*2+1 ----
    {
        half8 ya[2];
        #pragma unroll
        for (int kc = 0; kc < 2; kc++)
            ya[kc] = *(const half8*)&Ylds[fl * 72 + kc * 32 + sub * 8];
        #pragma unroll
        for (int j = 0; j < 2; j++) {
            const int nt = wv * 2 + j;
            floatx4 a1 = {};
            #pragma unroll
            for (int kc = 0; kc < 2; kc++) {
                half8 bf = *(const half8*)&Wf1[((kc * 8 + nt) * 64 + lane) * 8];
                a1 = __builtin_amdgcn_mfma_f32_16x16x32_f16(ya[kc], bf, a1, 0, 0, 0);
            }
            float bv = b1[nt * 16 + fl];
            #pragma unroll
            for (int reg = 0; reg < 4; reg++) {
                float v = fmaxf(a1[reg] + bv, 0.f);
                X1l[(sub * 4 + reg) * X1S + nt * 16 + fl] = (_Float16)v;
            }
        }
    }
    __syncthreads();
    // ---- G2: gh = dinv * (X1 @ W2), wave handles col-tile wv ----
    {
        floatx4 a2 = {};
        #pragma unroll
        for (int kc = 0; kc < 4; kc++) {
            half8 xa = *(const half8*)&X1l[fl * X1S + kc * 32 + sub * 8];
            half8 bf = *(const half8*)&Wf2[((kc * 4 + wv) * 64 + lane) * 8];
            a2 = __builtin_amdgcn_mfma_f32_16x16x32_f16(xa, bf, a2, 0, 0, 0);
        }
        #pragma unroll
        for (int reg = 0; reg < 4; reg++) {
            int row = sub * 4 + reg;
            float v = a2[reg] * ldv[row];
            gh[(size_t)(n0 + row) * 64 + wv * 16 + fl] = (_Float16)v;
        }
    }
}

// ---------------------------------------------------------------------------
// Pull aggregation (layer 2), NODE-PER-SUB: block = 16 nodes, 4 waves; each
// wave's 4 sub-quads own ONE node; lane accumulates its 8-byte slice
// in-register. Predicated gathers; full-64-lane self-load; compacted store.
// ---------------------------------------------------------------------------
__global__ __launch_bounds__(256) void pull2_k(const __half* __restrict__ sh,
        const unsigned short* __restrict__ csr, const int2* __restrict__ rp2,
        const float* __restrict__ dinv, const float* __restrict__ bias,
        float* __restrict__ out) {
    __shared__ unsigned short lcsr[LCAP];
    __shared__ int lrs[PBN], lre[PBN];
    __shared__ float ldv[PBN];
    const int tid = threadIdx.x;
    const int n0 = blockIdx.x * PBN;             // padded node base (no straddle)
    const int g2 = n0 >= NPAD;
    const int gbase = g2 ? NPAD : 0;
    if (tid < PBN) {
        int2 r = rp2[n0 + tid];
        lrs[tid] = r.x; lre[tid] = r.y;
        ldv[tid] = dinv[n0 + tid];
    }
    __syncthreads();
    const int wb = lrs[0];
    const int wcnt = min(lre[PBN - 1] - wb, LCAP);
    for (int i = tid; i < wcnt; i += 256) lcsr[i] = csr[wb + i];
    __syncthreads();
    const int wv = tid >> 6, lane = tid & 63;
    const int sub = lane >> 4, fl = lane & 15;
    const int n = wv * 4 + sub;                  // this lane's node (0..15)
    const int d = n0 + n;
    const int jfull = lre[n] - wb;
    const int jb = min(lrs[n] - wb, wcnt);
    const int je = min(jfull, wcnt);
    float4 acc = {0.f, 0.f, 0.f, 0.f};
    for (int j = jb; j < je; j += 8) {
        uint2 u[8];
        #pragma unroll
        for (int k = 0; k < 8; k++) {
            uint2 v; v.x = 0u; v.y = 0u;
            int idx = j + k;
            if (idx < je) {                      // sub-uniform guard
                int s = (int)lcsr[idx] + gbase;
                v = *(const uint2*)&sh[(size_t)s * 64 + fl * 4];
            }
            u[k] = v;
        }
        #pragma unroll
        for (int k = 0; k < 8; k += 2) {
            __half2 pa = __hadd2(*(__half2*)&u[k].x, *(__half2*)&u[k + 1].x);
            __half2 pb = __hadd2(*(__half2*)&u[k].y, *(__half2*)&u[k + 1].y);
            float2 fa = __half22float2(pa), fb = __half22float2(pb);
            acc.x += fa.x; acc.y += fa.y; acc.z += fb.x; acc.w += fb.y;
        }
    }
    for (int j2 = je; j2 < jfull; j2++) {        // LCAP overflow: global, rare
        int s = (int)csr[wb + j2] + gbase;
        uint2 u = *(const uint2*)&sh[(size_t)s * 64 + fl * 4];
        float2 f0 = __half22float2(*(__half2*)&u.x);
        float2 f1 = __half22float2(*(__half2*)&u.y);
        acc.x += f0.x; acc.y += f0.y; acc.z += f1.x; acc.w += f1.y;
    }
    uint2 su = *(const uint2*)&sh[(size_t)d * 64 + fl * 4];
    float2 sf0 = __half22float2(*(__half2*)&su.x);
    float2 sf1 = __half22float2(*(__half2*)&su.y);
    float dv = ldv[n];
    float4 bv = *(const float4*)&bias[fl * 4];
    float4 o;
    o.x = fmaxf((acc.x + sf0.x) * dv + bv.x, 0.f);
    o.y = fmaxf((acc.y + sf0.y) * dv + bv.y, 0.f);
    o.z = fmaxf((acc.z + sf1.x) * dv + bv.z, 0.f);
    o.w = fmaxf((acc.w + sf1.y) * dv + bv.w, 0.f);
    int local = d - gbase;
    if (local < N_NODES) {
        size_t orow = (size_t)(g2 ? N_NODES + local : local);
        floatx4 ov; ov.x = o.x; ov.y = o.y; ov.z = o.z; ov.w = o.w;
        __builtin_nontemporal_store(ov, (floatx4*)&out[orow * 64 + fl * 4]);
    }
}

extern "C" void kernel_launch(void* const* d_in, const int* in_sizes, int n_in,
                              void* d_out, int out_size, void* d_ws, size_t ws_size,
                              hipStream_t stream) {
    const float* x1 = (const float*)d_in[0];
    const int*   e1 = (const int*)d_in[1];
    const float* x2 = (const float*)d_in[2];
    const int*   e2 = (const int*)d_in[3];
    const float* W1 = (const float*)d_in[4];
    const float* b1 = (const float*)d_in[5];
    const float* W2 = (const float*)d_in[6];
    const float* b2 = (const float*)d_in[7];
    float* out = (float*)d_out;

    // Workspace (~38 MB), 256 B-aligned chunks. No memset needed (no atomics).
    char* p = (char*)d_ws;
    auto alloc = [&](size_t bytes) { char* r = p; p += (bytes + 255) & ~(size_t)255; return r; };
    unsigned* blkbuf = (unsigned*)alloc((size_t)NEB * EPB * 4);          // 6.4 MB
    unsigned short* lofsM = (unsigned short*)alloc((size_t)NEB * (NBKT + 1) * 2);
    float*    dinv   = (float*)alloc((size_t)2 * NPAD * 4);
    int2*     rp2    = (int2*)alloc((size_t)2 * NPAD * 8);               // 803 KB
    unsigned short* csr = (unsigned short*)alloc((size_t)NBKT * BCAP * 2); // 4.8 MB
    __half*   sxh    = (__half*)alloc((size_t)2 * NPAD * 64 * 2);        // fp16 feats
    _Float16* gh     = (_Float16*)alloc((size_t)2 * NPAD * 64 * 2);      // fused out;
                                   // must NOT alias sxh (pull1g reads sxh while
                                   // writing gh)
    _Float16* Wf1    = (_Float16*)alloc(8192 * 2);
    _Float16* Wf2    = (_Float16*)alloc(8192 * 2);

    // ---- binning (atomic-free) + W fragment pack (fused) ----
    binA_k<<<NEB + 2, ATH, 0, stream>>>(e1, e2, W1, W2, blkbuf, lofsM, Wf1, Wf2);
    // ---- bucket gather + CSR + dinv + fp16 prescale ----
    buildB_k<<<NBKT, BTH, 0, stream>>>(lofsM, blkbuf, x1, x2, csr, rp2, dinv, sxh);
    // ---- layer 1 agg + BOTH weight GEMMs fused ----
    pull1g_k<<<2 * NPAD / PBN, 256, 0, stream>>>(
        sxh, csr, rp2, dinv, Wf1, b1, Wf2, gh);
    // ---- layer 2 agg + epilogue: out = relu(dinv*(sum+self)+b2) ----
    pull2_k<<<2 * NPAD / PBN, 256, 0, stream>>>(
        (const __half*)gh, csr, rp2, dinv, b2, out);
}

// Round 10
// 177.849 us; speedup vs baseline: 1.2952x; 1.0211x over previous
//
#include <hip/hip_runtime.h>
#include <hip/hip_fp16.h>

#define N_NODES 50000
#define N_EDGES 800000
#define NPAD    50176          // 196*256: graph-2 node base, bucket-aligned
#define NBKT    392            // (2*NPAD)/256 buckets of 256 nodes
#define BCAP    6144           // bucket capacity; mean 4082, sigma 64 -> +32 sigma
#define PBN     16             // nodes per pull block (NPAD % PBN == 0)
#define LCAP    1024           // staged csr window cap (mean 256, +48 sigma)
#define X1S     136            // LDS X1 stride (halfs): 272 B rows, 16B-aligned
#define EPB     4096           // measured-best (R3: 2048 worse, R6: 16384 worse)
#define NEB     ((2 * N_EDGES + EPB - 1) / EPB)   // 391 edge blocks
#define ATH     1024           // R8-verified: binA wide block (latency-chain)
#define BTH     512            // R8-verified: buildB wide block
static_assert(N_NODES < 65536, "u16 CSR requires local node ids < 65536");
static_assert(EPB <= 65536, "u16 sidx/lofsM requires EPB <= 65536");
static_assert(NEB <= BTH, "buildB segment scan assumes one segment per thread");
// R9-verified: zero-global-atomic binning (deterministic placement, fixed
// per-bucket CSR regions, rp2 = per-node {start,end}).
// R10: uint4 gathers in both pulls. Per node: two 8-lane half-groups (l8,h);
// half h gathers parity-h edges as 16B slices -> 4 gather instrs/round
// (was 8), 2x edges per instruction, 16B/lane sweet spot. One shfl_xor(8)
// merges halves. Epilogue offsets fl*4 -> l8*8+h*4 (same 16 offsets).
// LAYOUT RULE: all intermediate buffers indexed by PADDED gid (g*NPAD + i).
// Gather/GEMM feature buffers are fp16; all accumulation fp32 (MFMA C=f32).

typedef _Float16 __attribute__((ext_vector_type(8))) half8;
typedef float    __attribute__((ext_vector_type(4))) floatx4;

// Per-block edge-index stride detection (int64 vs int32): odd 32-bit words of
// little-endian int64 with values < 2^31 are all zero.
__device__ __forceinline__ int detect_stride_block(const int* raw1, int* sflag) {
    int odd = 0;
    for (int i = threadIdx.x; i < 2048; i += blockDim.x) odd |= raw1[2 * i + 1];
    if (threadIdx.x == 0) *sflag = 0;
    __syncthreads();
    if (odd) atomicOr(sflag, 1);
    __syncthreads();
    return *sflag ? 1 : 2;
}

// ---------------------------------------------------------------------------
// Pass A, NEB edge-blocks x EPB edges, 1024 threads, NO GLOBAL ATOMICS:
// stage + LDS hist -> guarded 512-H-S scan -> LDS counting sort -> contiguous
// coalesced flush to blkbuf[b*EPB..] + lofsM row (u16 offsets, 393/block).
// Entry: (dst_in_bucket << 16) | src_local. Blocks NEB/NEB+1 pack W1/W2.
// ---------------------------------------------------------------------------
__global__ __launch_bounds__(ATH) void binA_k(const int* __restrict__ raw1,
        const int* __restrict__ raw2, const float* __restrict__ W1,
        const float* __restrict__ W2, unsigned* __restrict__ blkbuf,
        unsigned short* __restrict__ lofsM, _Float16* __restrict__ Wf1,
        _Float16* __restrict__ Wf2) {
    const int tid = threadIdx.x;
    if (blockIdx.x >= NEB) {                 // fused wprep
        const int wsel = blockIdx.x - NEB;
        const float* W = wsel ? W2 : W1;
        _Float16* Wf = wsel ? Wf2 : Wf1;
        const int M = wsel ? 64 : 128;
        const int NT = M / 16;
        for (int i = tid; i < 8192; i += ATH) {           // 16 frags x 512
            int f = i >> 9, r = i & 511;
            int lane = r >> 3, j = r & 7;
            int kc = f / NT, nt = f % NT;
            int k = kc * 32 + (lane >> 4) * 8 + j;
            int m = nt * 16 + (lane & 15);
            Wf[i] = (_Float16)W[k * M + m];
        }
        return;
    }
    __shared__ unsigned ent[EPB];            // 16 KB
    __shared__ unsigned short ebkt[EPB];     // 8 KB
    __shared__ unsigned short sidx[EPB];     // 8 KB: bucket-sorted entry indices
    __shared__ unsigned hist[NBKT];
    __shared__ int lofs[NBKT], cur[NBKT];
    __shared__ int t2[512];
    __shared__ int sflag;
    const int stride = detect_stride_block(raw1, &sflag);
    for (int b = tid; b < NBKT; b += ATH) hist[b] = 0u;
    __syncthreads();
    const long long e0 = (long long)blockIdx.x * EPB;
    const int scnt = (int)min((long long)EPB, 2LL * N_EDGES - e0);
    #pragma unroll
    for (int it = 0; it < EPB / ATH; it++) {
        int i = it * ATH + tid;
        if (i < scnt) {
            long long e = e0 + i;
            int g2 = e >= N_EDGES;
            const int* raw = g2 ? raw2 : raw1;
            long long el = e - (g2 ? N_EDGES : 0);
            int s = raw[el * stride];
            int d = raw[((long long)N_EDGES + el) * stride];
            int gid = g2 * NPAD + d;
            int bkt = gid >> 8;
            ent[i] = ((unsigned)(gid & 255) << 16) | (unsigned)s;
            ebkt[i] = (unsigned short)bkt;
            atomicAdd(&hist[bkt], 1u);
        }
    }
    __syncthreads();
    // exclusive scan of hist -> lofs (guarded 512 Hillis-Steele) + lofsM row
    if (tid < 512) t2[tid] = (tid < NBKT) ? (int)hist[tid] : 0;
    __syncthreads();
    #pragma unroll
    for (int off = 1; off < 512; off <<= 1) {
        int a0 = (tid < 512 && tid >= off) ? t2[tid - off] : 0;
        __syncthreads();
        if (tid < 512) t2[tid] += a0;
        __syncthreads();
    }
    if (tid < NBKT) {
        int l = t2[tid] - (int)hist[tid];
        lofs[tid] = l; cur[tid] = l;
        lofsM[(size_t)blockIdx.x * (NBKT + 1) + tid] = (unsigned short)l;
    }
    if (tid == 0)
        lofsM[(size_t)blockIdx.x * (NBKT + 1) + NBKT] = (unsigned short)scnt;
    __syncthreads();
    // place entry indices in bucket-sorted order (LDS cursors)
    #pragma unroll
    for (int it = 0; it < EPB / ATH; it++) {
        int i = it * ATH + tid;
        if (i < scnt) {
            int bkt = (int)ebkt[i];
            int p = atomicAdd(&cur[bkt], 1);
            sidx[p] = (unsigned short)i;
        }
    }
    __syncthreads();
    // contiguous coalesced flush: blkbuf[b*EPB + i], i = sorted position
    #pragma unroll
    for (int it = 0; it < EPB / ATH; it++) {
        int i = it * ATH + tid;
        if (i < scnt)
            blkbuf[(size_t)blockIdx.x * EPB + i] = ent[(int)sidx[i]];
    }
}

// ---------------------------------------------------------------------------
// Pass B, 512 threads, one block per bucket k: gather the bucket's entries
// from NEB per-block segments (block-wide scan of segment counts -> LDS
// placement); per-node degree + rp2{start,end} + dinv; LDS-cursor CSR
// scatter into fixed region csr[k*BCAP..]; fused fp16 prescale.
// ---------------------------------------------------------------------------
__global__ __launch_bounds__(BTH) void buildB_k(const unsigned short* __restrict__ lofsM,
        const unsigned* __restrict__ blkbuf, const float* __restrict__ x1,
        const float* __restrict__ x2, unsigned short* __restrict__ csr,
        int2* __restrict__ rp2, float* __restrict__ dinv,
        __half* __restrict__ sxh) {
    __shared__ unsigned ent[BCAP];
    __shared__ int deg[256], cur[256];
    __shared__ int wsum8[8], wsum4[4];
    __shared__ int total_s;
    __shared__ float sdinv[256];
    const int k = blockIdx.x, tid = threadIdx.x;
    const int lane = tid & 63, w = tid >> 6;
    // segment sizes: thread t owns source block t
    int s0 = 0, sc = 0;
    if (tid < NEB) {
        s0 = (int)lofsM[(size_t)tid * (NBKT + 1) + k];
        sc = (int)lofsM[(size_t)tid * (NBKT + 1) + k + 1] - s0;
    }
    // block-wide exclusive scan of sc (8 wave scans + cross-wave prefix)
    int x = sc;
    #pragma unroll
    for (int off = 1; off < 64; off <<= 1) {
        int y = __shfl_up(x, off);
        if (lane >= off) x += y;
    }
    if (lane == 63) wsum8[w] = x;
    if (tid < 256) deg[tid] = 0;
    __syncthreads();
    int wpre = 0;
    #pragma unroll
    for (int i = 0; i < 8; i++) wpre += (i < w) ? wsum8[i] : 0;
    const int incl = x + wpre;
    const int ofs = incl - sc;
    if (tid == BTH - 1) total_s = incl;          // last thread holds the total
    __syncthreads();
    const int cnt = min(total_s, BCAP);
    // copy segments into ent (mean ~10.5 u32 per source block)
    if (sc > 0) {
        const unsigned* src = &blkbuf[(size_t)tid * EPB + s0];
        for (int i = 0; i < sc; i++) {
            int p = ofs + i;
            if (p < BCAP) ent[p] = src[i];
        }
    }
    __syncthreads();
    for (int i = tid; i < cnt; i += BTH) atomicAdd(&deg[ent[i] >> 16], 1);
    __syncthreads();
    if (tid < 256) {                             // waves 0-3: node scan
        const int v = deg[tid];
        int y = v;
        #pragma unroll
        for (int off = 1; off < 64; off <<= 1) {
            int z = __shfl_up(y, off);
            if (lane >= off) y += z;
        }
        if (lane == 63) wsum4[w] = y;
        cur[tid] = y - v;                        // wave-local exclusive
        const int gid = k * 256 + tid;
        float dv = rsqrtf((float)v + 1.0f);      // +1 self-loop
        dinv[gid] = dv;
        sdinv[tid] = dv;
    }
    __syncthreads();
    if (tid < 256) {
        const int v = deg[tid];
        int wp = 0;
        #pragma unroll
        for (int i = 0; i < 4; i++) wp += (i < w) ? wsum4[i] : 0;
        const int excl = cur[tid] + wp;
        cur[tid] = excl;
        const int gid = k * 256 + tid;
        int st = k * BCAP + excl;
        rp2[gid] = make_int2(st, st + v);
    }
    __syncthreads();
    for (int i = tid; i < cnt; i += BTH) {
        unsigned p = ent[i];
        int pos = atomicAdd(&cur[p >> 16], 1);   // pos < cnt <= BCAP
        csr[(size_t)k * BCAP + pos] = (unsigned short)(p & 0xFFFFu);
    }
    const int g2 = (k * 256) >= NPAD;
    const float* x0 = g2 ? x2 : x1;
    const int lbase = k * 256 - (g2 ? NPAD : 0);
    for (int i = tid; i < 256 * 16; i += BTH) {
        int n = i >> 4, q = i & 15;
        int local = lbase + n;
        __half2 lo = __floats2half2_rn(0.f, 0.f), hi = lo;
        if (local < N_NODES) {
            float4 vx = *(const float4*)&x0[((size_t)local * 16 + q) * 4];
            float dn = sdinv[n];
            lo = __floats2half2_rn(vx.x * dn, vx.y * dn);
            hi = __floats2half2_rn(vx.z * dn, vx.w * dn);
        }
        uint2 u; u.x = *(unsigned*)&lo; u.y = *(unsigned*)&hi;
        *(uint2*)&sxh[(size_t)(k * 256 + n) * 64 + q * 4] = u;
    }
}

// ---------------------------------------------------------------------------
// R10 gather core: node = 16-lane sub, split into two 8-lane halves (l8,h);
// half h gathers parity-h edges as uint4 (16B) -> 4 gather instrs per
// 8-edge round. shfl_xor(8) merges halves; lane's output slice = l8*8+h*4.
// Returns acc4 (4 fp32) for the lane's 4 output features + writes nothing.
// ---------------------------------------------------------------------------
__device__ __forceinline__ floatx4 gather_row8(const __half* __restrict__ sh,
        const unsigned short* __restrict__ lcsr, const unsigned short* __restrict__ csr,
        int wb, int jb, int je, int jfull, int gbase, int l8, int h) {
    float a0 = 0.f, a1 = 0.f, a2 = 0.f, a3 = 0.f,
          a4 = 0.f, a5 = 0.f, a6 = 0.f, a7 = 0.f;
    for (int j = jb; j < je; j += 8) {
        uint4 u[4];
        #pragma unroll
        for (int k = 0; k < 4; k++) {
            uint4 v; v.x = v.y = v.z = v.w = 0u;
            int idx = j + 2 * k + h;
            if (idx < je) {                      // 8-lane-uniform guard
                int s = (int)lcsr[idx] + gbase;
                v = *(const uint4*)&sh[(size_t)s * 64 + l8 * 8];
            }
            u[k] = v;
        }
        #pragma unroll
        for (int k = 0; k < 4; k += 2) {
            const unsigned* pa = (const unsigned*)&u[k];
            const unsigned* pb = (const unsigned*)&u[k + 1];
            __half2 s0 = __hadd2(*(__half2*)&pa[0], *(__half2*)&pb[0]);
            __half2 s1 = __hadd2(*(__half2*)&pa[1], *(__half2*)&pb[1]);
            __half2 s2 = __hadd2(*(__half2*)&pa[2], *(__half2*)&pb[2]);
            __half2 s3 = __hadd2(*(__half2*)&pa[3], *(__half2*)&pb[3]);
            float2 f0 = __half22float2(s0), f1 = __half22float2(s1);
            float2 f2 = __half22float2(s2), f3 = __half22float2(s3);
            a0 += f0.x; a1 += f0.y; a2 += f1.x; a3 += f1.y;
            a4 += f2.x; a5 += f2.y; a6 += f3.x; a7 += f3.y;
        }
    }
    for (int j2 = je + h; j2 < jfull; j2 += 2) { // LCAP overflow: global, rare
        int s = (int)csr[wb + j2] + gbase;
        uint4 v = *(const uint4*)&sh[(size_t)s * 64 + l8 * 8];
        const unsigned* pv = (const unsigned*)&v;
        float2 f0 = __half22float2(*(__half2*)&pv[0]);
        float2 f1 = __half22float2(*(__half2*)&pv[1]);
        float2 f2 = __half22float2(*(__half2*)&pv[2]);
        float2 f3 = __half22float2(*(__half2*)&pv[3]);
        a0 += f0.x; a1 += f0.y; a2 += f1.x; a3 += f1.y;
        a4 += f2.x; a5 += f2.y; a6 += f3.x; a7 += f3.y;
    }
    // merge the two half-groups (lane ^ 8 holds the other parity's partials)
    a0 += __shfl_xor(a0, 8); a1 += __shfl_xor(a1, 8);
    a2 += __shfl_xor(a2, 8); a3 += __shfl_xor(a3, 8);
    a4 += __shfl_xor(a4, 8); a5 += __shfl_xor(a5, 8);
    a6 += __shfl_xor(a6, 8); a7 += __shfl_xor(a7, 8);
    // lane's 4 output features = l8*8 + h*4 (static-index select by h)
    floatx4 r;
    r.x = h ? a4 : a0; r.y = h ? a5 : a1;
    r.z = h ? a6 : a2; r.w = h ? a7 : a3;
    return r;
}

// ---------------------------------------------------------------------------
// FUSED pull-1 + both weight GEMMs (R7-verified): Y -> LDS (stride 72),
// G1 = relu(Y@W1+b1) -> LDS X1 (stride 136), G2 = dinv*(X1@W2) -> gh.
// 32 MFMAs / block across 4 waves. gh MUST NOT alias sxh. rp2 = {start,end}.
// ---------------------------------------------------------------------------
__global__ __launch_bounds__(256) void pull1g_k(const __half* __restrict__ sh,
        const unsigned short* __restrict__ csr, const int2* __restrict__ rp2,
        const float* __restrict__ dinv, const _Float16* __restrict__ Wf1,
        const float* __restrict__ b1, const _Float16* __restrict__ Wf2,
        _Float16* __restrict__ gh) {
    __shared__ unsigned short lcsr[LCAP];
    __shared__ int lrs[PBN], lre[PBN];
    __shared__ float ldv[PBN];
    __shared__ _Float16 Ylds[16 * 72];           // 2.3 KB, row stride 144 B
    __shared__ _Float16 X1l[16 * X1S];           // 4.4 KB
    const int tid = threadIdx.x;
    const int n0 = blockIdx.x * PBN;             // padded node base (no straddle)
    const int g2 = n0 >= NPAD;
    const int gbase = g2 ? NPAD : 0;
    if (tid < PBN) {
        int2 r = rp2[n0 + tid];
        lrs[tid] = r.x; lre[tid] = r.y;
        ldv[tid] = dinv[n0 + tid];
    }
    __syncthreads();
    const int wb = lrs[0];
    const int wcnt = min(lre[PBN - 1] - wb, LCAP);   // rows contiguous in bucket
    for (int i = tid; i < wcnt; i += 256) lcsr[i] = csr[wb + i];
    __syncthreads();
    const int wv = tid >> 6, lane = tid & 63;
    const int sub = lane >> 4, fl = lane & 15;   // MFMA mapping (GEMM phases)
    const int l8 = lane & 7, h = (lane >> 3) & 1;
    const int n = wv * 4 + sub;                  // this lane's node (0..15)
    const int d = n0 + n;
    const int jfull = lre[n] - wb;
    const int jb = min(lrs[n] - wb, wcnt);
    const int je = min(jfull, wcnt);
    floatx4 acc = gather_row8(sh, lcsr, csr, wb, jb, je, jfull, gbase, l8, h);
    const int fo = l8 * 8 + h * 4;               // lane's 4 output features
    uint2 su = *(const uint2*)&sh[(size_t)d * 64 + fo];
    float2 sf0 = __half22float2(*(__half2*)&su.x);
    float2 sf1 = __half22float2(*(__half2*)&su.y);
    float dv = ldv[n];
    // Y row n, feats fo..fo+3 -> LDS (no global Y)
    __half2 lo = __floats2half2_rn((acc.x + sf0.x) * dv, (acc.y + sf0.y) * dv);
    __half2 hi = __floats2half2_rn((acc.z + sf1.x) * dv, (acc.w + sf1.y) * dv);
    uint2 yu; yu.x = *(unsigned*)&lo; yu.y = *(unsigned*)&hi;
    *(uint2*)&Ylds[n * 72 + fo] = yu;
    __syncthreads();
    // ---- G1: X1 = relu(Y @ W1 + b1), wave handles col-tiles wv*2, wv*2+1 ----
    {
        half8 ya[2];
        #pragma unroll
        for (int kc = 0; kc < 2; kc++)
            ya[kc] = *(const half8*)&Ylds[fl * 72 + kc * 32 + sub * 8];
        #pragma unroll
        for (int j = 0; j < 2; j++) {
            const int nt = wv * 2 + j;
            floatx4 a1 = {};
            #pragma unroll
            for (int kc = 0; kc < 2; kc++) {
                half8 bf = *(const half8*)&Wf1[((kc * 8 + nt) * 64 + lane) * 8];
                a1 = __builtin_amdgcn_mfma_f32_16x16x32_f16(ya[kc], bf, a1, 0, 0, 0);
            }
            float bv = b1[nt * 16 + fl];
            #pragma unroll
            for (int reg = 0; reg < 4; reg++) {
                float v = fmaxf(a1[reg] + bv, 0.f);
                X1l[(sub * 4 + reg) * X1S + nt * 16 + fl] = (_Float16)v;
            }
        }
    }
    __syncthreads();
    // ---- G2: gh = dinv * (X1 @ W2), wave handles col-tile wv ----
    {
        floatx4 a2 = {};
        #pragma unroll
        for (int kc = 0; kc < 4; kc++) {
            half8 xa = *(const half8*)&X1l[fl * X1S + kc * 32 + sub * 8];
            half8 bf = *(const half8*)&Wf2[((kc * 4 + wv) * 64 + lane) * 8];
            a2 = __builtin_amdgcn_mfma_f32_16x16x32_f16(xa, bf, a2, 0, 0, 0);
        }
        #pragma unroll
        for (int reg = 0; reg < 4; reg++) {
            int row = sub * 4 + reg;
            float v = a2[reg] * ldv[row];
            gh[(size_t)(n0 + row) * 64 + wv * 16 + fl] = (_Float16)v;
        }
    }
}

// ---------------------------------------------------------------------------
// Pull aggregation (layer 2): R10 uint4 gather core; epilogue on the lane's
// 4 output features (fo = l8*8 + h*4); compacted nontemporal store.
// ---------------------------------------------------------------------------
__global__ __launch_bounds__(256) void pull2_k(const __half* __restrict__ sh,
        const unsigned short* __restrict__ csr, const int2* __restrict__ rp2,
        const float* __restrict__ dinv, const float* __restrict__ bias,
        float* __restrict__ out) {
    __shared__ unsigned short lcsr[LCAP];
    __shared__ int lrs[PBN], lre[PBN];
    __shared__ float ldv[PBN];
    const int tid = threadIdx.x;
    const int n0 = blockIdx.x * PBN;             // padded node base (no straddle)
    const int g2 = n0 >= NPAD;
    const int gbase = g2 ? NPAD : 0;
    if (tid < PBN) {
        int2 r = rp2[n0 + tid];
        lrs[tid] = r.x; lre[tid] = r.y;
        ldv[tid] = dinv[n0 + tid];
    }
    __syncthreads();
    const int wb = lrs[0];
    const int wcnt = min(lre[PBN - 1] - wb, LCAP);
    for (int i = tid; i < wcnt; i += 256) lcsr[i] = csr[wb + i];
    __syncthreads();
    const int wv = tid >> 6, lane = tid & 63;
    const int sub = lane >> 4;
    const int l8 = lane & 7, h = (lane >> 3) & 1;
    const int n = wv * 4 + sub;                  // this lane's node (0..15)
    const int d = n0 + n;
    const int jfull = lre[n] - wb;
    const int jb = min(lrs[n] - wb, wcnt);
    const int je = min(jfull, wcnt);
    floatx4 acc = gather_row8(sh, lcsr, csr, wb, jb, je, jfull, gbase, l8, h);
    const int fo = l8 * 8 + h * 4;               // lane's 4 output features
    uint2 su = *(const uint2*)&sh[(size_t)d * 64 + fo];
    float2 sf0 = __half22float2(*(__half2*)&su.x);
    float2 sf1 = __half22float2(*(__half2*)&su.y);
    float dv = ldv[n];
    float4 bv = *(const float4*)&bias[fo];
    floatx4 o;
    o.x = fmaxf((acc.x + sf0.x) * dv + bv.x, 0.f);
    o.y = fmaxf((acc.y + sf0.y) * dv + bv.y, 0.f);
    o.z = fmaxf((acc.z + sf1.x) * dv + bv.z, 0.f);
    o.w = fmaxf((acc.w + sf1.y) * dv + bv.w, 0.f);
    int local = d - gbase;
    if (local < N_NODES) {
        size_t orow = (size_t)(g2 ? N_NODES + local : local);
        __builtin_nontemporal_store(o, (floatx4*)&out[orow * 64 + fo]);
    }
}

extern "C" void kernel_launch(void* const* d_in, const int* in_sizes, int n_in,
                              void* d_out, int out_size, void* d_ws, size_t ws_size,
                              hipStream_t stream) {
    const float* x1 = (const float*)d_in[0];
    const int*   e1 = (const int*)d_in[1];
    const float* x2 = (const float*)d_in[2];
    const int*   e2 = (const int*)d_in[3];
    const float* W1 = (const float*)d_in[4];
    const float* b1 = (const float*)d_in[5];
    const float* W2 = (const float*)d_in[6];
    const float* b2 = (const float*)d_in[7];
    float* out = (float*)d_out;

    // Workspace (~38 MB), 256 B-aligned chunks. No memset needed (no atomics).
    char* p = (char*)d_ws;
    auto alloc = [&](size_t bytes) { char* r = p; p += (bytes + 255) & ~(size_t)255; return r; };
    unsigned* blkbuf = (unsigned*)alloc((size_t)NEB * EPB * 4);          // 6.4 MB
    unsigned short* lofsM = (unsigned short*)alloc((size_t)NEB * (NBKT + 1) * 2);
    float*    dinv   = (float*)alloc((size_t)2 * NPAD * 4);
    int2*     rp2    = (int2*)alloc((size_t)2 * NPAD * 8);               // 803 KB
    unsigned short* csr = (unsigned short*)alloc((size_t)NBKT * BCAP * 2); // 4.8 MB
    __half*   sxh    = (__half*)alloc((size_t)2 * NPAD * 64 * 2);        // fp16 feats
    _Float16* gh     = (_Float16*)alloc((size_t)2 * NPAD * 64 * 2);      // fused out;
                                   // must NOT alias sxh (pull1g reads sxh while
                                   // writing gh)
    _Float16* Wf1    = (_Float16*)alloc(8192 * 2);
    _Float16* Wf2    = (_Float16*)alloc(8192 * 2);

    // ---- binning (atomic-free) + W fragment pack (fused) ----
    binA_k<<<NEB + 2, ATH, 0, stream>>>(e1, e2, W1, W2, blkbuf, lofsM, Wf1, Wf2);
    // ---- bucket gather + CSR + dinv + fp16 prescale ----
    buildB_k<<<NBKT, BTH, 0, stream>>>(lofsM, blkbuf, x1, x2, csr, rp2, dinv, sxh);
    // ---- layer 1 agg + BOTH weight GEMMs fused ----
    pull1g_k<<<2 * NPAD / PBN, 256, 0, stream>>>(
        sxh, csr, rp2, dinv, Wf1, b1, Wf2, gh);
    // ---- layer 2 agg + epilogue: out = relu(dinv*(sum+self)+b2) ----
    pull2_k<<<2 * NPAD / PBN, 256, 0, stream>>>(
        (const __half*)gh, csr, rp2, dinv, b2, out);
}

// Round 11
// 177.257 us; speedup vs baseline: 1.2995x; 1.0033x over previous
//
#include <hip/hip_runtime.h>
#include <hip/hip_fp16.h>

#define N_NODES 50000
#define N_EDGES 800000
#define NPAD    50176          // 196*256: graph-2 node base, bucket-aligned
#define NBKT    392            // (2*NPAD)/256 buckets of 256 nodes
#define BCAP    6144           // bucket capacity; mean 4082, sigma 64 -> +32 sigma
#define PBN     16             // nodes per pull block (NPAD % PBN == 0)
#define LCAP    1024           // staged csr window cap (mean 256, +48 sigma)
#define X1S     136            // LDS X1 stride (halfs): 272 B rows, 16B-aligned
#define EPB     4096           // measured-best (R3: 2048 worse, R6: 16384 worse)
#define NEB     ((2 * N_EDGES + EPB - 1) / EPB)   // 391 edge blocks
#define ATH     1024           // R8-verified: binA wide block (latency-chain)
#define BTH     512            // R8-verified: buildB wide block
#define SRCH    25088          // R11: source-half split point (NPAD/2)
static_assert(N_NODES < 65536, "u16 CSR requires local node ids < 65536");
static_assert(EPB <= 65536, "u16 sidx/lofsM requires EPB <= 65536");
static_assert(NEB <= BTH, "buildB segment scan assumes one segment per thread");
// R9-verified: zero-global-atomic binning. R10-verified: uint4 gather core
// (small gain -> pulls are line-traffic bound, not instruction bound).
// R11: SRC-HALF PHASED CSR ROWS. Pulls gather from a 6.4MB region > 4MiB
// per-XCD L2 with ~16x reuse per source row -> L2 thrash. buildB now scatters
// each row's edges half-0-src first, half-1-src second (two LDS cursors).
// Blocks then touch half-0's 3.2MB early and half-1's 3.2MB late -> phase
// working set fits L2. Pull kernels UNCHANGED (they walk rows in CSR order).
// LAYOUT RULE: all intermediate buffers indexed by PADDED gid (g*NPAD + i).
// Gather/GEMM feature buffers are fp16; all accumulation fp32 (MFMA C=f32).

typedef _Float16 __attribute__((ext_vector_type(8))) half8;
typedef float    __attribute__((ext_vector_type(4))) floatx4;

// Per-block edge-index stride detection (int64 vs int32): odd 32-bit words of
// little-endian int64 with values < 2^31 are all zero.
__device__ __forceinline__ int detect_stride_block(const int* raw1, int* sflag) {
    int odd = 0;
    for (int i = threadIdx.x; i < 2048; i += blockDim.x) odd |= raw1[2 * i + 1];
    if (threadIdx.x == 0) *sflag = 0;
    __syncthreads();
    if (odd) atomicOr(sflag, 1);
    __syncthreads();
    return *sflag ? 1 : 2;
}

// ---------------------------------------------------------------------------
// Pass A, NEB edge-blocks x EPB edges, 1024 threads, NO GLOBAL ATOMICS:
// stage + LDS hist -> guarded 512-H-S scan -> LDS counting sort -> contiguous
// coalesced flush to blkbuf[b*EPB..] + lofsM row (u16 offsets, 393/block).
// Entry: (dst_in_bucket << 16) | src_local. Blocks NEB/NEB+1 pack W1/W2.
// ---------------------------------------------------------------------------
__global__ __launch_bounds__(ATH) void binA_k(const int* __restrict__ raw1,
        const int* __restrict__ raw2, const float* __restrict__ W1,
        const float* __restrict__ W2, unsigned* __restrict__ blkbuf,
        unsigned short* __restrict__ lofsM, _Float16* __restrict__ Wf1,
        _Float16* __restrict__ Wf2) {
    const int tid = threadIdx.x;
    if (blockIdx.x >= NEB) {                 // fused wprep
        const int wsel = blockIdx.x - NEB;
        const float* W = wsel ? W2 : W1;
        _Float16* Wf = wsel ? Wf2 : Wf1;
        const int M = wsel ? 64 : 128;
        const int NT = M / 16;
        for (int i = tid; i < 8192; i += ATH) {           // 16 frags x 512
            int f = i >> 9, r = i & 511;
            int lane = r >> 3, j = r & 7;
            int kc = f / NT, nt = f % NT;
            int k = kc * 32 + (lane >> 4) * 8 + j;
            int m = nt * 16 + (lane & 15);
            Wf[i] = (_Float16)W[k * M + m];
        }
        return;
    }
    __shared__ unsigned ent[EPB];            // 16 KB
    __shared__ unsigned short ebkt[EPB];     // 8 KB
    __shared__ unsigned short sidx[EPB];     // 8 KB: bucket-sorted entry indices
    __shared__ unsigned hist[NBKT];
    __shared__ int lofs[NBKT], cur[NBKT];
    __shared__ int t2[512];
    __shared__ int sflag;
    const int stride = detect_stride_block(raw1, &sflag);
    for (int b = tid; b < NBKT; b += ATH) hist[b] = 0u;
    __syncthreads();
    const long long e0 = (long long)blockIdx.x * EPB;
    const int scnt = (int)min((long long)EPB, 2LL * N_EDGES - e0);
    #pragma unroll
    for (int it = 0; it < EPB / ATH; it++) {
        int i = it * ATH + tid;
        if (i < scnt) {
            long long e = e0 + i;
            int g2 = e >= N_EDGES;
            const int* raw = g2 ? raw2 : raw1;
            long long el = e - (g2 ? N_EDGES : 0);
            int s = raw[el * stride];
            int d = raw[((long long)N_EDGES + el) * stride];
            int gid = g2 * NPAD + d;
            int bkt = gid >> 8;
            ent[i] = ((unsigned)(gid & 255) << 16) | (unsigned)s;
            ebkt[i] = (unsigned short)bkt;
            atomicAdd(&hist[bkt], 1u);
        }
    }
    __syncthreads();
    // exclusive scan of hist -> lofs (guarded 512 Hillis-Steele) + lofsM row
    if (tid < 512) t2[tid] = (tid < NBKT) ? (int)hist[tid] : 0;
    __syncthreads();
    #pragma unroll
    for (int off = 1; off < 512; off <<= 1) {
        int a0 = (tid < 512 && tid >= off) ? t2[tid - off] : 0;
        __syncthreads();
        if (tid < 512) t2[tid] += a0;
        __syncthreads();
    }
    if (tid < NBKT) {
        int l = t2[tid] - (int)hist[tid];
        lofs[tid] = l; cur[tid] = l;
        lofsM[(size_t)blockIdx.x * (NBKT + 1) + tid] = (unsigned short)l;
    }
    if (tid == 0)
        lofsM[(size_t)blockIdx.x * (NBKT + 1) + NBKT] = (unsigned short)scnt;
    __syncthreads();
    // place entry indices in bucket-sorted order (LDS cursors)
    #pragma unroll
    for (int it = 0; it < EPB / ATH; it++) {
        int i = it * ATH + tid;
        if (i < scnt) {
            int bkt = (int)ebkt[i];
            int p = atomicAdd(&cur[bkt], 1);
            sidx[p] = (unsigned short)i;
        }
    }
    __syncthreads();
    // contiguous coalesced flush: blkbuf[b*EPB + i], i = sorted position
    #pragma unroll
    for (int it = 0; it < EPB / ATH; it++) {
        int i = it * ATH + tid;
        if (i < scnt)
            blkbuf[(size_t)blockIdx.x * EPB + i] = ent[(int)sidx[i]];
    }
}

// ---------------------------------------------------------------------------
// Pass B, 512 threads, one block per bucket k: gather the bucket's entries
// from NEB per-block segments; per-node degree (+ half-0 degree) + rp2 +
// dinv; two-cursor LDS scatter into fixed region csr[k*BCAP..] so each
// row's edges are ordered src-half-0 then src-half-1 (R11); fp16 prescale.
// ---------------------------------------------------------------------------
__global__ __launch_bounds__(BTH) void buildB_k(const unsigned short* __restrict__ lofsM,
        const unsigned* __restrict__ blkbuf, const float* __restrict__ x1,
        const float* __restrict__ x2, unsigned short* __restrict__ csr,
        int2* __restrict__ rp2, float* __restrict__ dinv,
        __half* __restrict__ sxh) {
    __shared__ unsigned ent[BCAP];
    __shared__ int deg[256], deg0[256], cur[256], cur1[256];
    __shared__ int wsum8[8], wsum4[4];
    __shared__ int total_s;
    __shared__ float sdinv[256];
    const int k = blockIdx.x, tid = threadIdx.x;
    const int lane = tid & 63, w = tid >> 6;
    // segment sizes: thread t owns source block t
    int s0 = 0, sc = 0;
    if (tid < NEB) {
        s0 = (int)lofsM[(size_t)tid * (NBKT + 1) + k];
        sc = (int)lofsM[(size_t)tid * (NBKT + 1) + k + 1] - s0;
    }
    // block-wide exclusive scan of sc (8 wave scans + cross-wave prefix)
    int x = sc;
    #pragma unroll
    for (int off = 1; off < 64; off <<= 1) {
        int y = __shfl_up(x, off);
        if (lane >= off) x += y;
    }
    if (lane == 63) wsum8[w] = x;
    if (tid < 256) { deg[tid] = 0; deg0[tid] = 0; }
    __syncthreads();
    int wpre = 0;
    #pragma unroll
    for (int i = 0; i < 8; i++) wpre += (i < w) ? wsum8[i] : 0;
    const int incl = x + wpre;
    const int ofs = incl - sc;
    if (tid == BTH - 1) total_s = incl;          // last thread holds the total
    __syncthreads();
    const int cnt = min(total_s, BCAP);
    // copy segments into ent (mean ~10.5 u32 per source block)
    if (sc > 0) {
        const unsigned* src = &blkbuf[(size_t)tid * EPB + s0];
        for (int i = 0; i < sc; i++) {
            int p = ofs + i;
            if (p < BCAP) ent[p] = src[i];
        }
    }
    __syncthreads();
    for (int i = tid; i < cnt; i += BTH) {
        unsigned p = ent[i];
        atomicAdd(&deg[p >> 16], 1);
        if ((p & 0xFFFFu) < SRCH) atomicAdd(&deg0[p >> 16], 1);
    }
    __syncthreads();
    if (tid < 256) {                             // waves 0-3: node scan
        const int v = deg[tid];
        int y = v;
        #pragma unroll
        for (int off = 1; off < 64; off <<= 1) {
            int z = __shfl_up(y, off);
            if (lane >= off) y += z;
        }
        if (lane == 63) wsum4[w] = y;
        cur[tid] = y - v;                        // wave-local exclusive
        const int gid = k * 256 + tid;
        float dv = rsqrtf((float)v + 1.0f);      // +1 self-loop
        dinv[gid] = dv;
        sdinv[tid] = dv;
    }
    __syncthreads();
    if (tid < 256) {
        const int v = deg[tid];
        int wp = 0;
        #pragma unroll
        for (int i = 0; i < 4; i++) wp += (i < w) ? wsum4[i] : 0;
        const int excl = cur[tid] + wp;
        cur[tid] = excl;                         // half-0 cursor
        cur1[tid] = excl + deg0[tid];            // half-1 cursor
        const int gid = k * 256 + tid;
        int st = k * BCAP + excl;
        rp2[gid] = make_int2(st, st + v);
    }
    __syncthreads();
    for (int i = tid; i < cnt; i += BTH) {
        unsigned p = ent[i];
        int n = p >> 16;
        int pos = ((p & 0xFFFFu) < SRCH) ? atomicAdd(&cur[n], 1)
                                         : atomicAdd(&cur1[n], 1);
        csr[(size_t)k * BCAP + pos] = (unsigned short)(p & 0xFFFFu);
    }
    const int g2 = (k * 256) >= NPAD;
    const float* x0 = g2 ? x2 : x1;
    const int lbase = k * 256 - (g2 ? NPAD : 0);
    for (int i = tid; i < 256 * 16; i += BTH) {
        int n = i >> 4, q = i & 15;
        int local = lbase + n;
        __half2 lo = __floats2half2_rn(0.f, 0.f), hi = lo;
        if (local < N_NODES) {
            float4 vx = *(const float4*)&x0[((size_t)local * 16 + q) * 4];
            float dn = sdinv[n];
            lo = __floats2half2_rn(vx.x * dn, vx.y * dn);
            hi = __floats2half2_rn(vx.z * dn, vx.w * dn);
        }
        uint2 u; u.x = *(unsigned*)&lo; u.y = *(unsigned*)&hi;
        *(uint2*)&sxh[(size_t)(k * 256 + n) * 64 + q * 4] = u;
    }
}

// ---------------------------------------------------------------------------
// R10 gather core: node = 16-lane sub, split into two 8-lane halves (l8,h);
// half h gathers parity-h edges as uint4 (16B) -> 4 gather instrs per
// 8-edge round. shfl_xor(8) merges halves; lane's output slice = l8*8+h*4.
// ---------------------------------------------------------------------------
__device__ __forceinline__ floatx4 gather_row8(const __half* __restrict__ sh,
        const unsigned short* __restrict__ lcsr, const unsigned short* __restrict__ csr,
        int wb, int jb, int je, int jfull, int gbase, int l8, int h) {
    float a0 = 0.f, a1 = 0.f, a2 = 0.f, a3 = 0.f,
          a4 = 0.f, a5 = 0.f, a6 = 0.f, a7 = 0.f;
    for (int j = jb; j < je; j += 8) {
        uint4 u[4];
        #pragma unroll
        for (int k = 0; k < 4; k++) {
            uint4 v; v.x = v.y = v.z = v.w = 0u;
            int idx = j + 2 * k + h;
            if (idx < je) {                      // 8-lane-uniform guard
                int s = (int)lcsr[idx] + gbase;
                v = *(const uint4*)&sh[(size_t)s * 64 + l8 * 8];
            }
            u[k] = v;
        }
        #pragma unroll
        for (int k = 0; k < 4; k += 2) {
            const unsigned* pa = (const unsigned*)&u[k];
            const unsigned* pb = (const unsigned*)&u[k + 1];
            __half2 s0 = __hadd2(*(__half2*)&pa[0], *(__half2*)&pb[0]);
            __half2 s1 = __hadd2(*(__half2*)&pa[1], *(__half2*)&pb[1]);
            __half2 s2 = __hadd2(*(__half2*)&pa[2], *(__half2*)&pb[2]);
            __half2 s3 = __hadd2(*(__half2*)&pa[3], *(__half2*)&pb[3]);
            float2 f0 = __half22float2(s0), f1 = __half22float2(s1);
            float2 f2 = __half22float2(s2), f3 = __half22float2(s3);
            a0 += f0.x; a1 += f0.y; a2 += f1.x; a3 += f1.y;
            a4 += f2.x; a5 += f2.y; a6 += f3.x; a7 += f3.y;
        }
    }
    for (int j2 = je + h; j2 < jfull; j2 += 2) { // LCAP overflow: global, rare
        int s = (int)csr[wb + j2] + gbase;
        uint4 v = *(const uint4*)&sh[(size_t)s * 64 + l8 * 8];
        const unsigned* pv = (const unsigned*)&v;
        float2 f0 = __half22float2(*(__half2*)&pv[0]);
        float2 f1 = __half22float2(*(__half2*)&pv[1]);
        float2 f2 = __half22float2(*(__half2*)&pv[2]);
        float2 f3 = __half22float2(*(__half2*)&pv[3]);
        a0 += f0.x; a1 += f0.y; a2 += f1.x; a3 += f1.y;
        a4 += f2.x; a5 += f2.y; a6 += f3.x; a7 += f3.y;
    }
    // merge the two half-groups (lane ^ 8 holds the other parity's partials)
    a0 += __shfl_xor(a0, 8); a1 += __shfl_xor(a1, 8);
    a2 += __shfl_xor(a2, 8); a3 += __shfl_xor(a3, 8);
    a4 += __shfl_xor(a4, 8); a5 += __shfl_xor(a5, 8);
    a6 += __shfl_xor(a6, 8); a7 += __shfl_xor(a7, 8);
    floatx4 r;
    r.x = h ? a4 : a0; r.y = h ? a5 : a1;
    r.z = h ? a6 : a2; r.w = h ? a7 : a3;
    return r;
}

// ---------------------------------------------------------------------------
// FUSED pull-1 + both weight GEMMs (R7-verified): Y -> LDS (stride 72),
// G1 = relu(Y@W1+b1) -> LDS X1 (stride 136), G2 = dinv*(X1@W2) -> gh.
// 32 MFMAs / block across 4 waves. gh MUST NOT alias sxh. rp2 = {start,end}.
// ---------------------------------------------------------------------------
__global__ __launch_bounds__(256) void pull1g_k(const __half* __restrict__ sh,
        const unsigned short* __restrict__ csr, const int2* __restrict__ rp2,
        const float* __restrict__ dinv, const _Float16* __restrict__ Wf1,
        const float* __restrict__ b1, const _Float16* __restrict__ Wf2,
        _Float16* __restrict__ gh) {
    __shared__ unsigned short lcsr[LCAP];
    __shared__ int lrs[PBN], lre[PBN];
    __shared__ float ldv[PBN];
    __shared__ _Float16 Ylds[16 * 72];           // 2.3 KB, row stride 144 B
    __shared__ _Float16 X1l[16 * X1S];           // 4.4 KB
    const int tid = threadIdx.x;
    const int n0 = blockIdx.x * PBN;             // padded node base (no straddle)
    const int g2 = n0 >= NPAD;
    const int gbase = g2 ? NPAD : 0;
    if (tid < PBN) {
        int2 r = rp2[n0 + tid];
        lrs[tid] = r.x; lre[tid] = r.y;
        ldv[tid] = dinv[n0 + tid];
    }
    __syncthreads();
    const int wb = lrs[0];
    const int wcnt = min(lre[PBN - 1] - wb, LCAP);   // rows contiguous in bucket
    for (int i = tid; i < wcnt; i += 256) lcsr[i] = csr[wb + i];
    __syncthreads();
    const int wv = tid >> 6, lane = tid & 63;
    const int sub = lane >> 4, fl = lane & 15;   // MFMA mapping (GEMM phases)
    const int l8 = lane & 7, h = (lane >> 3) & 1;
    const int n = wv * 4 + sub;                  // this lane's node (0..15)
    const int d = n0 + n;
    const int jfull = lre[n] - wb;
    const int jb = min(lrs[n] - wb, wcnt);
    const int je = min(jfull, wcnt);
    floatx4 acc = gather_row8(sh, lcsr, csr, wb, jb, je, jfull, gbase, l8, h);
    const int fo = l8 * 8 + h * 4;               // lane's 4 output features
    uint2 su = *(const uint2*)&sh[(size_t)d * 64 + fo];
    float2 sf0 = __half22float2(*(__half2*)&su.x);
    float2 sf1 = __half22float2(*(__half2*)&su.y);
    float dv = ldv[n];
    // Y row n, feats fo..fo+3 -> LDS (no global Y)
    __half2 lo = __floats2half2_rn((acc.x + sf0.x) * dv, (acc.y + sf0.y) * dv);
    __half2 hi = __floats2half2_rn((acc.z + sf1.x) * dv, (acc.w + sf1.y) * dv);
    uint2 yu; yu.x = *(unsigned*)&lo; yu.y = *(unsigned*)&hi;
    *(uint2*)&Ylds[n * 72 + fo] = yu;
    __syncthreads();
    // ---- G1: X1 = relu(Y @ W1 + b1), wave handles col-tiles wv*2, wv*2+1 ----
    {
        half8 ya[2];
        #pragma unroll
        for (int kc = 0; kc < 2; kc++)
            ya[kc] = *(const half8*)&Ylds[fl * 72 + kc * 32 + sub * 8];
        #pragma unroll
        for (int j = 0; j < 2; j++) {
            const int nt = wv * 2 + j;
            floatx4 a1 = {};
            #pragma unroll
            for (int kc = 0; kc < 2; kc++) {
                half8 bf = *(const half8*)&Wf1[((kc * 8 + nt) * 64 + lane) * 8];
                a1 = __builtin_amdgcn_mfma_f32_16x16x32_f16(ya[kc], bf, a1, 0, 0, 0);
            }
            float bv = b1[nt * 16 + fl];
            #pragma unroll
            for (int reg = 0; reg < 4; reg++) {
                float v = fmaxf(a1[reg] + bv, 0.f);
                X1l[(sub * 4 + reg) * X1S + nt * 16 + fl] = (_Float16)v;
            }
        }
    }
    __syncthreads();
    // ---- G2: gh = dinv * (X1 @ W2), wave handles col-tile wv ----
    {
        floatx4 a2 = {};
        #pragma unroll
        for (int kc = 0; kc < 4; kc++) {
            half8 xa = *(const half8*)&X1l[fl * X1S + kc * 32 + sub * 8];
            half8 bf = *(const half8*)&Wf2[((kc * 4 + wv) * 64 + lane) * 8];
            a2 = __builtin_amdgcn_mfma_f32_16x16x32_f16(xa, bf, a2, 0, 0, 0);
        }
        #pragma unroll
        for (int reg = 0; reg < 4; reg++) {
            int row = sub * 4 + reg;
            float v = a2[reg] * ldv[row];
            gh[(size_t)(n0 + row) * 64 + wv * 16 + fl] = (_Float16)v;
        }
    }
}

// ---------------------------------------------------------------------------
// Pull aggregation (layer 2): R10 uint4 gather core; epilogue on the lane's
// 4 output features (fo = l8*8 + h*4); compacted nontemporal store.
// ---------------------------------------------------------------------------
__global__ __launch_bounds__(256) void pull2_k(const __half* __restrict__ sh,
        const unsigned short* __restrict__ csr, const int2* __restrict__ rp2,
        const float* __restrict__ dinv, const float* __restrict__ bias,
        float* __restrict__ out) {
    __shared__ unsigned short lcsr[LCAP];
    __shared__ int lrs[PBN], lre[PBN];
    __shared__ float ldv[PBN];
    const int tid = threadIdx.x;
    const int n0 = blockIdx.x * PBN;             // padded node base (no straddle)
    const int g2 = n0 >= NPAD;
    const int gbase = g2 ? NPAD : 0;
    if (tid < PBN) {
        int2 r = rp2[n0 + tid];
        lrs[tid] = r.x; lre[tid] = r.y;
        ldv[tid] = dinv[n0 + tid];
    }
    __syncthreads();
    const int wb = lrs[0];
    const int wcnt = min(lre[PBN - 1] - wb, LCAP);
    for (int i = tid; i < wcnt; i += 256) lcsr[i] = csr[wb + i];
    __syncthreads();
    const int wv = tid >> 6, lane = tid & 63;
    const int sub = lane >> 4;
    const int l8 = lane & 7, h = (lane >> 3) & 1;
    const int n = wv * 4 + sub;                  // this lane's node (0..15)
    const int d = n0 + n;
    const int jfull = lre[n] - wb;
    const int jb = min(lrs[n] - wb, wcnt);
    const int je = min(jfull, wcnt);
    floatx4 acc = gather_row8(sh, lcsr, csr, wb, jb, je, jfull, gbase, l8, h);
    const int fo = l8 * 8 + h * 4;               // lane's 4 output features
    uint2 su = *(const uint2*)&sh[(size_t)d * 64 + fo];
    float2 sf0 = __half22float2(*(__half2*)&su.x);
    float2 sf1 = __half22float2(*(__half2*)&su.y);
    float dv = ldv[n];
    float4 bv = *(const float4*)&bias[fo];
    floatx4 o;
    o.x = fmaxf((acc.x + sf0.x) * dv + bv.x, 0.f);
    o.y = fmaxf((acc.y + sf0.y) * dv + bv.y, 0.f);
    o.z = fmaxf((acc.z + sf1.x) * dv + bv.z, 0.f);
    o.w = fmaxf((acc.w + sf1.y) * dv + bv.w, 0.f);
    int local = d - gbase;
    if (local < N_NODES) {
        size_t orow = (size_t)(g2 ? N_NODES + local : local);
        __builtin_nontemporal_store(o, (floatx4*)&out[orow * 64 + fo]);
    }
}

extern "C" void kernel_launch(void* const* d_in, const int* in_sizes, int n_in,
                              void* d_out, int out_size, void* d_ws, size_t ws_size,
                              hipStream_t stream) {
    const float* x1 = (const float*)d_in[0];
    const int*   e1 = (const int*)d_in[1];
    const float* x2 = (const float*)d_in[2];
    const int*   e2 = (const int*)d_in[3];
    const float* W1 = (const float*)d_in[4];
    const float* b1 = (const float*)d_in[5];
    const float* W2 = (const float*)d_in[6];
    const float* b2 = (const float*)d_in[7];
    float* out = (float*)d_out;

    // Workspace (~38 MB), 256 B-aligned chunks. No memset needed (no atomics).
    char* p = (char*)d_ws;
    auto alloc = [&](size_t bytes) { char* r = p; p += (bytes + 255) & ~(size_t)255; return r; };
    unsigned* blkbuf = (unsigned*)alloc((size_t)NEB * EPB * 4);          // 6.4 MB
    unsigned short* lofsM = (unsigned short*)alloc((size_t)NEB * (NBKT + 1) * 2);
    float*    dinv   = (float*)alloc((size_t)2 * NPAD * 4);
    int2*     rp2    = (int2*)alloc((size_t)2 * NPAD * 8);               // 803 KB
    unsigned short* csr = (unsigned short*)alloc((size_t)NBKT * BCAP * 2); // 4.8 MB
    __half*   sxh    = (__half*)alloc((size_t)2 * NPAD * 64 * 2);        // fp16 feats
    _Float16* gh     = (_Float16*)alloc((size_t)2 * NPAD * 64 * 2);      // fused out;
                                   // must NOT alias sxh (pull1g reads sxh while
                                   // writing gh)
    _Float16* Wf1    = (_Float16*)alloc(8192 * 2);
    _Float16* Wf2    = (_Float16*)alloc(8192 * 2);

    // ---- binning (atomic-free) + W fragment pack (fused) ----
    binA_k<<<NEB + 2, ATH, 0, stream>>>(e1, e2, W1, W2, blkbuf, lofsM, Wf1, Wf2);
    // ---- bucket gather + CSR (src-half phased rows) + dinv + prescale ----
    buildB_k<<<NBKT, BTH, 0, stream>>>(lofsM, blkbuf, x1, x2, csr, rp2, dinv, sxh);
    // ---- layer 1 agg + BOTH weight GEMMs fused ----
    pull1g_k<<<2 * NPAD / PBN, 256, 0, stream>>>(
        sxh, csr, rp2, dinv, Wf1, b1, Wf2, gh);
    // ---- layer 2 agg + epilogue: out = relu(dinv*(sum+self)+b2) ----
    pull2_k<<<2 * NPAD / PBN, 256, 0, stream>>>(
        (const __half*)gh, csr, rp2, dinv, b2, out);
}